// Round 6
// baseline (4448.777 us; speedup 1.0000x reference)
//
#include <hip/hip_runtime.h>
#include <math.h>

typedef unsigned short u16;
typedef unsigned int u32;

#define D_DIM 2048
#define N_ROWS 4096
#define EPS_DIAG 1e-3f
#define NS_ITERS 16  // fallback path only

typedef __attribute__((ext_vector_type(8))) short bf16x8;
typedef __attribute__((ext_vector_type(4))) float f32x4;

__device__ __forceinline__ u16 f2bf(float f) {
  u32 u = __float_as_uint(f);
  u += 0x7fffu + ((u >> 16) & 1u);
  return (u16)(u >> 16);
}
__device__ __forceinline__ float bf2f(u16 h) {
  return __uint_as_float(((u32)h) << 16);
}

#define GLD16(g, l)                                        \
  __builtin_amdgcn_global_load_lds(                        \
      (const __attribute__((address_space(1))) void*)(g),  \
      (__attribute__((address_space(3))) void*)(l), 16, 0, 0)

// ---------------- column statistics (mean / rstd, ddof=1) ----------------

__global__ __launch_bounds__(256)
void k_colstats(const float* __restrict__ z, float* __restrict__ sum_,
                float* __restrict__ ssq_) {
  const int c = blockIdx.x * 256 + threadIdx.x;
  const int r0 = blockIdx.y * (N_ROWS / 16);
  float s = 0.f, q = 0.f;
#pragma unroll 8
  for (int r = 0; r < N_ROWS / 16; ++r) {
    float v = z[(size_t)(r0 + r) * D_DIM + c];
    s += v;
    q += v * v;
  }
  atomicAdd(&sum_[c], s);
  atomicAdd(&ssq_[c], q);
}

__global__ __launch_bounds__(256)
void k_finalize_stats(float* stat) {
  const int t = blockIdx.x * 256 + threadIdx.x;
  const int g = t >> 11;
  const int c = t & (D_DIM - 1);
  float* base = stat + g * 2 * D_DIM;
  float s = base[c];
  float q = base[D_DIM + c];
  float mean = s * (1.0f / N_ROWS);
  float var = (q - (float)N_ROWS * mean * mean) * (1.0f / (N_ROWS - 1));
  var = fmaxf(var, 1e-30f);
  base[c] = mean;
  base[D_DIM + c] = 1.0f / sqrtf(var);
}

// ================== FAST PATH (needs 128MB + 64KB workspace) ==================
// Buffer pool: 8 units of 16 MB. A D x D matrix occupies ONE unit
// (h at +0: 8 MB, l at +8MB: 8 MB). The transposed z-split Zt[D][N] needs
// 16 MB PER component: Zh occupies ALL of U0, Zl ALL of U1.

// standardize + split + TRANSPOSE: z[N][D] -> Zt[D][N] bf16 h/l
__global__ __launch_bounds__(256)
void k_zsplit_t(const float* __restrict__ z, const float* __restrict__ mean,
                const float* __restrict__ rstd, u16* __restrict__ Zth,
                u16* __restrict__ Ztl) {
  __shared__ float T[64 * 72];
  const int t = threadIdx.x;
  const int r0 = blockIdx.x * 64;  // row tile of z (N dim)
  const int c0 = blockIdx.y * 64;  // col tile of z (D dim)
#pragma unroll
  for (int p = 0; p < 4; ++p) {
    int row = p * 16 + (t >> 4);
    int c4 = t & 15;
    float4 v = *(const float4*)(z + (size_t)(r0 + row) * D_DIM + c0 + c4 * 4);
    *(float4*)&T[row * 72 + c4 * 4] = v;
  }
  __syncthreads();
  const int c = c0 + (t >> 2);
  const float m = mean[c];
  const float r = rstd[c];
  const int cc = t >> 2;
#pragma unroll
  for (int g = 0; g < 2; ++g) {
    int rbase = g * 32 + (t & 3) * 8;
    u16 hs[8], ls[8];
#pragma unroll
    for (int i = 0; i < 8; ++i) {
      float x = (T[(rbase + i) * 72 + cc] - m) * r;
      hs[i] = f2bf(x);
      ls[i] = f2bf(x - bf2f(hs[i]));
    }
    uint4 ph, pl;
    ph.x = (u32)hs[0] | ((u32)hs[1] << 16);
    ph.y = (u32)hs[2] | ((u32)hs[3] << 16);
    ph.z = (u32)hs[4] | ((u32)hs[5] << 16);
    ph.w = (u32)hs[6] | ((u32)hs[7] << 16);
    pl.x = (u32)ls[0] | ((u32)ls[1] << 16);
    pl.y = (u32)ls[2] | ((u32)ls[3] << 16);
    pl.z = (u32)ls[4] | ((u32)ls[5] << 16);
    pl.w = (u32)ls[6] | ((u32)ls[7] << 16);
    size_t o = (size_t)c * N_ROWS + r0 + rbase;
    *(uint4*)(Zth + o) = ph;
    *(uint4*)(Ztl + o) = pl;
  }
}

// Unified split-bf16 MFMA GEMM: C = diag*I + pm*(X * W^T), X:[128-tile][K],
// W:[64-tile][K] row-major. Both operands staged via global_load_lds (no
// VALU pack in K-loop). Dual-layout output via per-wave LDS transpose.
#define FINVC 1
#define FFROB 2
#define FTRACE 4
#define FCOL 8
#define FROW 16

__global__ __launch_bounds__(256)
void k_nn(const u16* __restrict__ Xh, const u16* __restrict__ Xl,
          const u16* __restrict__ Wh, const u16* __restrict__ Wl,
          u16* __restrict__ Crh, u16* __restrict__ Crl, u16* __restrict__ Cch,
          u16* __restrict__ Ccl, float* __restrict__ scal, int K, float diag,
          float pmul, int flags, int tidx) {
  __shared__ u16 lds[24576];
  const int tid = threadIdx.x;
  const int lane = tid & 63;
  const int w = tid >> 6;
  const int I = blockIdx.y * 128;
  const int J = blockIdx.x * 64;

  size_t xro[2];
  int xbase[2];
#pragma unroll
  for (int p = 0; p < 2; ++p) {
    int s = p * 256 + w * 64 + lane;
    int m = ((s >> 6) << 4) + (s & 15);
    int qq = (s >> 4) & 3;
    xro[p] = (size_t)(I + m) * K + qq * 8;
    xbase[p] = (p * 256 + w * 64) * 8;
  }
  size_t wro;
  {
    int n = w * 16 + (lane & 15);
    wro = (size_t)(J + n) * K + (lane >> 4) * 8;
  }
  const int wb0 = (w * 64) * 8;

  f32x4 acc[2][4];
#pragma unroll
  for (int i = 0; i < 2; ++i)
#pragma unroll
    for (int j = 0; j < 4; ++j) acc[i][j] = (f32x4){0.f, 0.f, 0.f, 0.f};

#define NN_STAGE(k1, buf)                                      \
  {                                                            \
    _Pragma("unroll") for (int p = 0; p < 2; ++p) {            \
      GLD16(Xh + xro[p] + (k1), &lds[(buf) + xbase[p]]);       \
      GLD16(Xl + xro[p] + (k1), &lds[(buf) + 4096 + xbase[p]]);\
    }                                                          \
    GLD16(Wh + wro + (k1), &lds[(buf) + 8192 + wb0]);          \
    GLD16(Wl + wro + (k1), &lds[(buf) + 10240 + wb0]);         \
  }

  NN_STAGE(0, 0);
  __syncthreads();
  const int nk = K >> 5;
  for (int k = 0; k < nk; ++k) {
    const int cur = (k & 1) * 12288;
    const int nxt = 12288 - cur;
    if (k + 1 < nk) NN_STAGE((k + 1) * 32, nxt);
    bf16x8 fxh[2], fxl[2], fwh[4], fwl[4];
#pragma unroll
    for (int i = 0; i < 2; ++i) {
      int sl = ((w * 2 + i) * 64 + lane) * 8;
      fxh[i] = *(const bf16x8*)&lds[cur + sl];
      fxl[i] = *(const bf16x8*)&lds[cur + 4096 + sl];
    }
#pragma unroll
    for (int j = 0; j < 4; ++j) {
      int sl = (j * 64 + lane) * 8;
      fwh[j] = *(const bf16x8*)&lds[cur + 8192 + sl];
      fwl[j] = *(const bf16x8*)&lds[cur + 10240 + sl];
    }
#pragma unroll
    for (int i = 0; i < 2; ++i)
#pragma unroll
      for (int j = 0; j < 4; ++j) {
        acc[i][j] = __builtin_amdgcn_mfma_f32_16x16x32_bf16(fxh[i], fwh[j],
                                                            acc[i][j], 0, 0, 0);
        acc[i][j] = __builtin_amdgcn_mfma_f32_16x16x32_bf16(fxh[i], fwl[j],
                                                            acc[i][j], 0, 0, 0);
        acc[i][j] = __builtin_amdgcn_mfma_f32_16x16x32_bf16(fxl[i], fwh[j],
                                                            acc[i][j], 0, 0, 0);
      }
    __syncthreads();
  }
#undef NN_STAGE

  const int qd = lane >> 4;
  const int nl = lane & 15;
  float pm = pmul;
  if (flags & FINVC) pm = pmul / sqrtf(scal[0]);

#define NN_VAL(i, j, r, out)                           \
  {                                                    \
    int gi_ = I + w * 32 + (i)*16 + qd * 4 + (r);      \
    int gj_ = J + (j)*16 + nl;                         \
    out = pm * acc[i][j][r];                           \
    if (gi_ == gj_) out += diag;                       \
  }

  if (flags & (FFROB | FTRACE)) {
    float fs = 0.f, ts = 0.f;
#pragma unroll
    for (int i = 0; i < 2; ++i)
#pragma unroll
      for (int j = 0; j < 4; ++j)
#pragma unroll
        for (int r = 0; r < 4; ++r) {
          float v;
          NN_VAL(i, j, r, v);
          fs += v * v;
          int gi = I + w * 32 + i * 16 + qd * 4 + r;
          int gj = J + j * 16 + nl;
          if (gi == gj) ts += v;
        }
#pragma unroll
    for (int o = 32; o > 0; o >>= 1) {
      fs += __shfl_down(fs, o, 64);
      ts += __shfl_down(ts, o, 64);
    }
    float* red = (float*)lds;
    if (lane == 0) {
      red[w] = fs;
      red[4 + w] = ts;
    }
    __syncthreads();
    if (tid == 0) {
      if (flags & FFROB) atomicAdd(&scal[0], red[0] + red[1] + red[2] + red[3]);
      if (flags & FTRACE)
        atomicAdd(&scal[tidx], red[4] + red[5] + red[6] + red[7]);
    }
    __syncthreads();
  }

  // dual-layout store via per-wave LDS transpose (wave region: 32x72 u16).
  // barriers make the write->transposed-read ordering explicit.
  const int wbp = w * 2304;
  for (int half = 0; half < 2; ++half) {
#pragma unroll
    for (int i = 0; i < 2; ++i)
#pragma unroll
      for (int j = 0; j < 4; ++j)
#pragma unroll
        for (int r = 0; r < 4; ++r) {
          float v;
          NN_VAL(i, j, r, v);
          u16 hv = f2bf(v);
          u16 sv = half ? f2bf(v - bf2f(hv)) : hv;
          lds[wbp + (i * 16 + qd * 4 + r) * 72 + j * 16 + nl] = sv;
        }
    __syncthreads();
    if (flags & FROW) {
      u16* dst = half ? Crl : Crh;
#pragma unroll
      for (int p2 = 0; p2 < 4; ++p2) {
        int rr = lane >> 1;
        int ch = (lane & 1) + p2 * 2;
        bf16x8 vv = *(const bf16x8*)&lds[wbp + rr * 72 + ch * 8];
        *(bf16x8*)(dst + (size_t)(I + w * 32 + rr) * D_DIM + J + ch * 8) = vv;
      }
    }
    if (flags & FCOL) {
      u16* dst = half ? Ccl : Cch;
#pragma unroll
      for (int jj = 0; jj < 4; ++jj) {
        int c = jj * 16 + (lane >> 2);
        int run = (lane & 3) * 8;
        u16 tp[8];
#pragma unroll
        for (int r2 = 0; r2 < 8; ++r2) tp[r2] = lds[wbp + (run + r2) * 72 + c];
        uint4 pk;
        pk.x = (u32)tp[0] | ((u32)tp[1] << 16);
        pk.y = (u32)tp[2] | ((u32)tp[3] << 16);
        pk.z = (u32)tp[4] | ((u32)tp[5] << 16);
        pk.w = (u32)tp[6] | ((u32)tp[7] << 16);
        *(uint4*)(dst + (size_t)(J + c) * D_DIM + I + w * 32 + run) = pk;
      }
    }
    __syncthreads();
  }
#undef NN_VAL
}

// T1 = 3I - M/c in BOTH layouts (row from Mr, col from Mt)
__global__ __launch_bounds__(256)
void k_t1(const u16* __restrict__ Mrh, const u16* __restrict__ Mrl,
          const u16* __restrict__ Mth, const u16* __restrict__ Mtl,
          const float* __restrict__ scal, u16* __restrict__ Trh,
          u16* __restrict__ Trl, u16* __restrict__ Tth, u16* __restrict__ Ttl) {
  size_t t = (size_t)blockIdx.x * 256 + threadIdx.x;
  float invc = 1.0f / sqrtf(scal[0]);
  size_t e = t * 4;
  int i = (int)(e >> 11);
  int j0 = (int)(e & (D_DIM - 1));
#pragma unroll
  for (int pass = 0; pass < 2; ++pass) {
    const u16* sh = pass ? Mth : Mrh;
    const u16* sl = pass ? Mtl : Mrl;
    u16* dh = pass ? Tth : Trh;
    u16* dl = pass ? Ttl : Trl;
    uint2 hv = ((const uint2*)sh)[t];
    uint2 lv = ((const uint2*)sl)[t];
    u16 hs[4] = {(u16)(hv.x & 0xffff), (u16)(hv.x >> 16), (u16)(hv.y & 0xffff),
                 (u16)(hv.y >> 16)};
    u16 ls[4] = {(u16)(lv.x & 0xffff), (u16)(lv.x >> 16), (u16)(lv.y & 0xffff),
                 (u16)(lv.y >> 16)};
    u16 th[4], tl[4];
#pragma unroll
    for (int c = 0; c < 4; ++c) {
      float m = bf2f(hs[c]) + bf2f(ls[c]);
      float tv = ((i == j0 + c) ? 3.0f : 0.0f) - m * invc;
      th[c] = f2bf(tv);
      tl[c] = f2bf(tv - bf2f(th[c]));
    }
    ((uint2*)dh)[t] = make_uint2((u32)th[0] | ((u32)th[1] << 16),
                                 (u32)th[2] | ((u32)th[3] << 16));
    ((uint2*)dl)[t] = make_uint2((u32)tl[0] | ((u32)tl[1] << 16),
                                 (u32)tl[2] | ((u32)tl[3] << 16));
  }
}

// dot(A, B) elementwise over h/l pairs -> double accumulator
__global__ __launch_bounds__(256)
void k_trdot(const u16* __restrict__ Ah, const u16* __restrict__ Al,
             const u16* __restrict__ Bh, const u16* __restrict__ Bl,
             double* __restrict__ acc) {
  size_t t = (size_t)blockIdx.x * 256 + threadIdx.x;
  uint2 ah = ((const uint2*)Ah)[t], al = ((const uint2*)Al)[t];
  uint2 bh = ((const uint2*)Bh)[t], bl = ((const uint2*)Bl)[t];
  float s = 0.f;
  u32 ha[4] = {ah.x & 0xffffu, ah.x >> 16, ah.y & 0xffffu, ah.y >> 16};
  u32 la[4] = {al.x & 0xffffu, al.x >> 16, al.y & 0xffffu, al.y >> 16};
  u32 hb[4] = {bh.x & 0xffffu, bh.x >> 16, bh.y & 0xffffu, bh.y >> 16};
  u32 lb[4] = {bl.x & 0xffffu, bl.x >> 16, bl.y & 0xffffu, bl.y >> 16};
#pragma unroll
  for (int c = 0; c < 4; ++c)
    s += (bf2f((u16)ha[c]) + bf2f((u16)la[c])) *
         (bf2f((u16)hb[c]) + bf2f((u16)lb[c]));
#pragma unroll
  for (int o = 32; o > 0; o >>= 1) s += __shfl_down(s, o, 64);
  __shared__ float red[4];
  if ((threadIdx.x & 63) == 0) red[threadIdx.x >> 6] = s;
  __syncthreads();
  if (threadIdx.x == 0)
    atomicAdd(acc, (double)(red[0] + red[1] + red[2] + red[3]));
}

// out = trA + trB - sqrt(c) * dot   (trC = sqrt(c)*trY15, trY15 = dot/2)
__global__ void k_final2(const float* __restrict__ scal,
                         const double* __restrict__ dot,
                         float* __restrict__ out) {
  out[0] = scal[1] + scal[2] - sqrtf(sqrtf(scal[0])) * (float)dot[0];
}

// ================== FALLBACK PATH (round-4, 64MB-proven) ==================

__global__ __launch_bounds__(256)
void k_zsplit(const float* __restrict__ z, const float* __restrict__ mean,
              const float* __restrict__ rstd, u16* __restrict__ zh,
              u16* __restrict__ zl) {
  size_t t = (size_t)blockIdx.x * 256 + threadIdx.x;
  int ci = (int)(t & 511);
  float4 v = ((const float4*)z)[t];
  float4 m = ((const float4*)mean)[ci];
  float4 r = ((const float4*)rstd)[ci];
  float x[4] = {(v.x - m.x) * r.x, (v.y - m.y) * r.y, (v.z - m.z) * r.z,
                (v.w - m.w) * r.w};
  u16 h[4], l[4];
#pragma unroll
  for (int i = 0; i < 4; ++i) {
    h[i] = f2bf(x[i]);
    l[i] = f2bf(x[i] - bf2f(h[i]));
  }
  ((uint2*)zh)[t] = make_uint2((u32)h[0] | ((u32)h[1] << 16),
                               (u32)h[2] | ((u32)h[3] << 16));
  ((uint2*)zl)[t] = make_uint2((u32)l[0] | ((u32)l[1] << 16),
                               (u32)l[2] | ((u32)l[3] << 16));
}

__global__ __launch_bounds__(256)
void k_gram_mm(const u16* __restrict__ zh, const u16* __restrict__ zl,
               u16* __restrict__ Oh, u16* __restrict__ Ol) {
  __shared__ u16 lds[24576];
  const int tid = threadIdx.x;
  const int lane = tid & 63;
  const int w = tid >> 6;
  const int I = blockIdx.y * 128;
  const int J = blockIdx.x * 64;
  const int kp = tid >> 4;
  const int nc = tid & 15;
  const int qq = kp >> 2;
  const int kd = (kp & 3) * 2;
  const size_t aro = (size_t)(2 * kp) * D_DIM + I + nc * 8;
  const size_t bro = (size_t)(2 * kp) * D_DIM + J + nc * 4;
  union U4 { uint4 v; u16 s[8]; };
  union U2 { uint2 v; u16 s[4]; };
  U4 ah0, ah1, al0, al1;
  U2 bh0, bh1, bl0, bl1;
  f32x4 acc[2][4];
#pragma unroll
  for (int i = 0; i < 2; ++i)
#pragma unroll
    for (int j = 0; j < 4; ++j) acc[i][j] = (f32x4){0.f, 0.f, 0.f, 0.f};
#define GRAM_LOAD(k1)                         \
  {                                           \
    size_t ao = aro + (size_t)(k1)*D_DIM;     \
    size_t bo = bro + (size_t)(k1)*D_DIM;     \
    ah0.v = *(const uint4*)(zh + ao);         \
    ah1.v = *(const uint4*)(zh + ao + D_DIM); \
    al0.v = *(const uint4*)(zl + ao);         \
    al1.v = *(const uint4*)(zl + ao + D_DIM); \
    bh0.v = *(const uint2*)(zh + bo);         \
    bh1.v = *(const uint2*)(zh + bo + D_DIM); \
    bl0.v = *(const uint2*)(zl + bo);         \
    bl1.v = *(const uint2*)(zl + bo + D_DIM); \
  }
#define GRAM_PACK(buf)                                                       \
  {                                                                          \
    _Pragma("unroll") for (int j = 0; j < 8; ++j) {                          \
      int mc = nc * 8 + j;                                                   \
      int t2 = mc >> 4, ml = mc & 15;                                        \
      int slot = (t2 * 64 + qq * 16 + ml) ^ t2;                              \
      *(u32*)&lds[(buf) + slot * 8 + kd] =                                   \
          (u32)ah0.s[j] | ((u32)ah1.s[j] << 16);                             \
      *(u32*)&lds[(buf) + 4096 + slot * 8 + kd] =                            \
          (u32)al0.s[j] | ((u32)al1.s[j] << 16);                             \
    }                                                                        \
    _Pragma("unroll") for (int j = 0; j < 4; ++j) {                          \
      int n = nc * 4 + j;                                                    \
      int u = n >> 4, nl = n & 15;                                           \
      int slot = (u * 64 + qq * 16 + nl) ^ u;                                \
      *(u32*)&lds[(buf) + 8192 + slot * 8 + kd] =                            \
          (u32)bh0.s[j] | ((u32)bh1.s[j] << 16);                             \
      *(u32*)&lds[(buf) + 10240 + slot * 8 + kd] =                           \
          (u32)bl0.s[j] | ((u32)bl1.s[j] << 16);                             \
    }                                                                        \
  }
  GRAM_LOAD(0);
  GRAM_PACK(0);
  __syncthreads();
  for (int k = 0; k < N_ROWS / 32; ++k) {
    const int cur = (k & 1) * 12288;
    const int nxt = 12288 - cur;
    if (k < N_ROWS / 32 - 1) GRAM_LOAD((k + 1) * 32);
    bf16x8 fah[2], fal[2], fbh[4], fbl[4];
#pragma unroll
    for (int i = 0; i < 2; ++i) {
      int t2 = w * 2 + i;
      int sl = (t2 * 64 + lane) ^ t2;
      fah[i] = *(const bf16x8*)&lds[cur + sl * 8];
      fal[i] = *(const bf16x8*)&lds[cur + 4096 + sl * 8];
    }
#pragma unroll
    for (int j = 0; j < 4; ++j) {
      int sl = (j * 64 + lane) ^ j;
      fbh[j] = *(const bf16x8*)&lds[cur + 8192 + sl * 8];
      fbl[j] = *(const bf16x8*)&lds[cur + 10240 + sl * 8];
    }
#pragma unroll
    for (int i = 0; i < 2; ++i)
#pragma unroll
      for (int j = 0; j < 4; ++j) {
        acc[i][j] = __builtin_amdgcn_mfma_f32_16x16x32_bf16(fah[i], fbh[j],
                                                            acc[i][j], 0, 0, 0);
        acc[i][j] = __builtin_amdgcn_mfma_f32_16x16x32_bf16(fah[i], fbl[j],
                                                            acc[i][j], 0, 0, 0);
        acc[i][j] = __builtin_amdgcn_mfma_f32_16x16x32_bf16(fal[i], fbh[j],
                                                            acc[i][j], 0, 0, 0);
      }
    if (k < N_ROWS / 32 - 1) GRAM_PACK(nxt);
    __syncthreads();
  }
  const int qd = lane >> 4;
  const int nl = lane & 15;
#pragma unroll
  for (int i = 0; i < 2; ++i)
#pragma unroll
    for (int j = 0; j < 4; ++j)
#pragma unroll
      for (int r = 0; r < 4; ++r) {
        int gi = I + w * 32 + i * 16 + qd * 4 + r;
        int gj = J + j * 16 + nl;
        float v = acc[i][j][r] + ((gi == gj) ? EPS_DIAG : 0.f);
        u16 h = f2bf(v);
        u16 l = f2bf(v - bf2f(h));
        Oh[(size_t)gi * D_DIM + gj] = h;
        Ol[(size_t)gi * D_DIM + gj] = l;
      }
#undef GRAM_LOAD
#undef GRAM_PACK
}

template <int MODE>
__global__ __launch_bounds__(256)
void k_mm(const u16* __restrict__ Ph, const u16* __restrict__ Pl,
          const u16* __restrict__ Qh, const u16* __restrict__ Ql,
          u16* __restrict__ Ch, u16* __restrict__ Cl,
          const float* __restrict__ scal) {
  __shared__ u16 lds[24576];
  const int tid = threadIdx.x;
  const int lane = tid & 63;
  const int w = tid >> 6;
  const int I = blockIdx.y * 128;
  const int J = blockIdx.x * 64;
  const int kp = tid >> 4;
  const int nc = tid & 15;
  const int qq = kp >> 2;
  const int kd = (kp & 3) * 2;
  size_t aro[2];
  int acl[2], abase[2];
#pragma unroll
  for (int p = 0; p < 2; ++p) {
    int s = p * 256 + w * 64 + lane;
    aro[p] = (size_t)(I + (s >> 6) * 16 + (s & 15)) * D_DIM;
    acl[p] = ((s >> 4) & 3) * 8;
    abase[p] = (p * 256 + w * 64) * 8;
  }
  const size_t bro = (size_t)(2 * kp) * D_DIM + J + nc * 4;
  union U2 { uint2 v; u16 s[4]; };
  U2 bh0, bh1, bl0, bl1;
  f32x4 acc[2][4];
#pragma unroll
  for (int i = 0; i < 2; ++i)
#pragma unroll
    for (int j = 0; j < 4; ++j) acc[i][j] = (f32x4){0.f, 0.f, 0.f, 0.f};
#define MM_STAGE_A(k1, buf)                                              \
  {                                                                      \
    _Pragma("unroll") for (int p = 0; p < 2; ++p) {                      \
      GLD16(Ph + aro[p] + (k1) + acl[p], &lds[(buf) + abase[p]]);        \
      GLD16(Pl + aro[p] + (k1) + acl[p], &lds[(buf) + 4096 + abase[p]]); \
    }                                                                    \
  }
#define MM_LOAD_B(k1)                         \
  {                                           \
    size_t bo = bro + (size_t)(k1)*D_DIM;     \
    bh0.v = *(const uint2*)(Qh + bo);         \
    bh1.v = *(const uint2*)(Qh + bo + D_DIM); \
    bl0.v = *(const uint2*)(Ql + bo);         \
    bl1.v = *(const uint2*)(Ql + bo + D_DIM); \
  }
#define MM_PACK_B(buf)                                                       \
  {                                                                          \
    _Pragma("unroll") for (int j = 0; j < 4; ++j) {                          \
      int n = nc * 4 + j;                                                    \
      int u = n >> 4, nl2 = n & 15;                                          \
      int slot = (u * 64 + qq * 16 + nl2) ^ u;                               \
      *(u32*)&lds[(buf) + 8192 + slot * 8 + kd] =                            \
          (u32)bh0.s[j] | ((u32)bh1.s[j] << 16);                             \
      *(u32*)&lds[(buf) + 10240 + slot * 8 + kd] =                           \
          (u32)bl0.s[j] | ((u32)bl1.s[j] << 16);                             \
    }                                                                        \
  }
  MM_STAGE_A(0, 0);
  MM_LOAD_B(0);
  MM_PACK_B(0);
  __syncthreads();
  for (int k = 0; k < D_DIM / 32; ++k) {
    const int cur = (k & 1) * 12288;
    const int nxt = 12288 - cur;
    if (k < D_DIM / 32 - 1) {
      MM_STAGE_A((k + 1) * 32, nxt);
      MM_LOAD_B((k + 1) * 32);
    }
    bf16x8 fah[2], fal[2], fbh[4], fbl[4];
#pragma unroll
    for (int i = 0; i < 2; ++i) {
      int t2 = w * 2 + i;
      fah[i] = *(const bf16x8*)&lds[cur + (t2 * 64 + lane) * 8];
      fal[i] = *(const bf16x8*)&lds[cur + 4096 + (t2 * 64 + lane) * 8];
    }
#pragma unroll
    for (int j = 0; j < 4; ++j) {
      int sl = (j * 64 + lane) ^ j;
      fbh[j] = *(const bf16x8*)&lds[cur + 8192 + sl * 8];
      fbl[j] = *(const bf16x8*)&lds[cur + 10240 + sl * 8];
    }
#pragma unroll
    for (int i = 0; i < 2; ++i)
#pragma unroll
      for (int j = 0; j < 4; ++j) {
        acc[i][j] = __builtin_amdgcn_mfma_f32_16x16x32_bf16(fah[i], fbh[j],
                                                            acc[i][j], 0, 0, 0);
        acc[i][j] = __builtin_amdgcn_mfma_f32_16x16x32_bf16(fah[i], fbl[j],
                                                            acc[i][j], 0, 0, 0);
        acc[i][j] = __builtin_amdgcn_mfma_f32_16x16x32_bf16(fal[i], fbh[j],
                                                            acc[i][j], 0, 0, 0);
      }
    if (k < D_DIM / 32 - 1) MM_PACK_B(nxt);
    __syncthreads();
  }
  float mul = (MODE == 2) ? 0.5f : 1.0f;
  if (MODE == 3) mul = 0.5f / sqrtf(scal[0]);
  const int qd = lane >> 4;
  const int nl = lane & 15;
#pragma unroll
  for (int i = 0; i < 2; ++i)
#pragma unroll
    for (int j = 0; j < 4; ++j)
#pragma unroll
      for (int r = 0; r < 4; ++r) {
        int gi = I + w * 32 + i * 16 + qd * 4 + r;
        int gj = J + j * 16 + nl;
        float v = acc[i][j][r];
        if (MODE == 1)
          v = ((gi == gj) ? 3.0f : 0.0f) - v;
        else
          v *= mul;
        u16 h = f2bf(v);
        u16 l = f2bf(v - bf2f(h));
        Ch[(size_t)gi * D_DIM + gj] = h;
        Cl[(size_t)gi * D_DIM + gj] = l;
      }
#undef MM_STAGE_A
#undef MM_LOAD_B
#undef MM_PACK_B
}

__global__ __launch_bounds__(256)
void k_frob_hl(const u16* __restrict__ mh, const u16* __restrict__ ml,
               float* __restrict__ c2) {
  size_t t = (size_t)blockIdx.x * 256 + threadIdx.x;
  uint2 hv = ((const uint2*)mh)[t];
  uint2 lv = ((const uint2*)ml)[t];
  float v0 = bf2f((u16)(hv.x & 0xffff)) + bf2f((u16)(lv.x & 0xffff));
  float v1 = bf2f((u16)(hv.x >> 16)) + bf2f((u16)(lv.x >> 16));
  float v2 = bf2f((u16)(hv.y & 0xffff)) + bf2f((u16)(lv.y & 0xffff));
  float v3 = bf2f((u16)(hv.y >> 16)) + bf2f((u16)(lv.y >> 16));
  float q = v0 * v0 + v1 * v1 + v2 * v2 + v3 * v3;
#pragma unroll
  for (int o = 32; o > 0; o >>= 1) q += __shfl_down(q, o, 64);
  __shared__ float red[4];
  if ((threadIdx.x & 63) == 0) red[threadIdx.x >> 6] = q;
  __syncthreads();
  if (threadIdx.x == 0) atomicAdd(c2, red[0] + red[1] + red[2] + red[3]);
}

__global__ __launch_bounds__(256)
void k_t1z1(const u16* __restrict__ Mh, const u16* __restrict__ Ml,
            const float* __restrict__ scal, u16* __restrict__ Th,
            u16* __restrict__ Tl, u16* __restrict__ Zh, u16* __restrict__ Zl) {
  size_t t = (size_t)blockIdx.x * 256 + threadIdx.x;
  float invc = 1.0f / sqrtf(scal[0]);
  size_t e = t * 4;
  int i = (int)(e >> 11);
  int j0 = (int)(e & (D_DIM - 1));
  uint2 hv = ((const uint2*)Mh)[t];
  uint2 lv = ((const uint2*)Ml)[t];
  u16 hs[4] = {(u16)(hv.x & 0xffff), (u16)(hv.x >> 16), (u16)(hv.y & 0xffff),
               (u16)(hv.y >> 16)};
  u16 ls[4] = {(u16)(lv.x & 0xffff), (u16)(lv.x >> 16), (u16)(lv.y & 0xffff),
               (u16)(lv.y >> 16)};
  u16 th[4], tl[4], zh[4], zl[4];
#pragma unroll
  for (int c = 0; c < 4; ++c) {
    float m = bf2f(hs[c]) + bf2f(ls[c]);
    float tv = ((i == j0 + c) ? 3.0f : 0.0f) - m * invc;
    th[c] = f2bf(tv);
    tl[c] = f2bf(tv - bf2f(th[c]));
    float zv = 0.5f * tv;
    zh[c] = f2bf(zv);
    zl[c] = f2bf(zv - bf2f(zh[c]));
  }
  ((uint2*)Th)[t] = make_uint2((u32)th[0] | ((u32)th[1] << 16),
                               (u32)th[2] | ((u32)th[3] << 16));
  ((uint2*)Tl)[t] = make_uint2((u32)tl[0] | ((u32)tl[1] << 16),
                               (u32)tl[2] | ((u32)tl[3] << 16));
  ((uint2*)Zh)[t] = make_uint2((u32)zh[0] | ((u32)zh[1] << 16),
                               (u32)zh[2] | ((u32)zh[3] << 16));
  ((uint2*)Zl)[t] = make_uint2((u32)zl[0] | ((u32)zl[1] << 16),
                               (u32)zl[2] | ((u32)zl[3] << 16));
}

__global__ __launch_bounds__(256)
void k_trace_hl(const u16* __restrict__ mh, const u16* __restrict__ ml,
                float* __restrict__ out) {
  __shared__ float red[256];
  float s = 0.f;
  for (int i = threadIdx.x; i < D_DIM; i += 256) {
    size_t d = (size_t)i * (D_DIM + 1);
    s += bf2f(mh[d]) + bf2f(ml[d]);
  }
  red[threadIdx.x] = s;
  __syncthreads();
  for (int o = 128; o > 0; o >>= 1) {
    if (threadIdx.x < o) red[threadIdx.x] += red[threadIdx.x + o];
    __syncthreads();
  }
  if (threadIdx.x == 0) out[0] = red[0];
}

__global__ __launch_bounds__(256)
void k_final(const u16* __restrict__ Yh, const u16* __restrict__ Yl,
             const float* __restrict__ scal, float* __restrict__ out) {
  __shared__ float red[256];
  float s = 0.f;
  for (int i = threadIdx.x; i < D_DIM; i += 256) {
    size_t d = (size_t)i * (D_DIM + 1);
    s += bf2f(Yh[d]) + bf2f(Yl[d]);
  }
  red[threadIdx.x] = s;
  __syncthreads();
  for (int o = 128; o > 0; o >>= 1) {
    if (threadIdx.x < o) red[threadIdx.x] += red[threadIdx.x + o];
    __syncthreads();
  }
  if (threadIdx.x == 0) {
    float sqrtc = sqrtf(sqrtf(scal[0]));
    out[0] = scal[1] + scal[2] - 2.0f * sqrtc * red[0];
  }
}

// ---------------- launch ----------------

extern "C" void kernel_launch(void* const* d_in, const int* in_sizes, int n_in,
                              void* d_out, int out_size, void* d_ws,
                              size_t ws_size, hipStream_t stream) {
  (void)in_sizes; (void)n_in; (void)out_size;
  const float* za = (const float*)d_in[0];
  const float* zb = (const float*)d_in[1];
  float* out = (float*)d_out;
  float* ws = (float*)d_ws;
  float* stat = ws;
  float* scal = ws + 4 * D_DIM;

  hipMemsetAsync(ws, 0, (4 * D_DIM + 16) * sizeof(float), stream);
  dim3 blk(256);
  k_colstats<<<dim3(8, 16), blk, 0, stream>>>(za, stat, stat + D_DIM);
  k_colstats<<<dim3(8, 16), blk, 0, stream>>>(zb, stat + 2 * D_DIM,
                                              stat + 3 * D_DIM);
  k_finalize_stats<<<16, blk, 0, stream>>>(stat);

  const size_t NEED = 65536ull + 8ull * 16 * 1024 * 1024;
  if (ws_size >= NEED) {
    // ================= FAST PATH =================
    char* pool = (char*)d_ws + 65536;
    auto uh = [&](int u) { return (u16*)(pool + (size_t)u * 16777216); };
    auto ul = [&](int u) {
      return (u16*)(pool + (size_t)u * 16777216 + 8388608);
    };
    // z-split: Zh = ALL of unit 0 (16 MB), Zl = ALL of unit 1 (16 MB).
    u16* Zh = (u16*)(pool);
    u16* Zl = (u16*)(pool + 16777216);
    dim3 gz(64, 32), gm(32, 16);
    // A = gram(za) -> U2 (trace->scal[1])
    k_zsplit_t<<<gz, blk, 0, stream>>>(za, stat, stat + D_DIM, Zh, Zl);
    k_nn<<<gm, blk, 0, stream>>>(Zh, Zl, Zh, Zl, uh(2), ul(2), uh(2), ul(2),
                                 scal, N_ROWS, EPS_DIAG, 1.0f, FROW | FTRACE,
                                 1);
    // B = gram(zb) -> U3 (trace->scal[2])
    k_zsplit_t<<<gz, blk, 0, stream>>>(zb, stat + 2 * D_DIM, stat + 3 * D_DIM,
                                       Zh, Zl);
    k_nn<<<gm, blk, 0, stream>>>(Zh, Zl, Zh, Zl, uh(3), ul(3), uh(3), ul(3),
                                 scal, N_ROWS, EPS_DIAG, 1.0f, FROW | FTRACE,
                                 2);
    // M = A*B -> row U4, col U5, frob->scal[0]  (B symmetric => W=B works)
    k_nn<<<gm, blk, 0, stream>>>(uh(2), ul(2), uh(3), ul(3), uh(4), ul(4),
                                 uh(5), ul(5), scal, D_DIM, 0.f, 1.0f,
                                 FROW | FCOL | FFROB, 0);
    // T1 = 3I - M/c : row->U6, col->U7
    k_t1<<<4096, blk, 0, stream>>>(uh(4), ul(4), uh(5), ul(5), scal, uh(6),
                                   ul(6), uh(7), ul(7));
    // Y1 = (0.5/c) M*T1 -> row U0, col U1 (z-split dead)
    k_nn<<<gm, blk, 0, stream>>>(uh(4), ul(4), uh(7), ul(7), uh(0), ul(0),
                                 uh(1), ul(1), scal, D_DIM, 0.f, 0.5f,
                                 FROW | FCOL | FINVC, 0);
    // T2 = 3I - 0.5*T1*Y1 -> row U2, col U3 (A,B dead; Z1 = T1/2 implicit)
    k_nn<<<gm, blk, 0, stream>>>(uh(6), ul(6), uh(1), ul(1), uh(2), ul(2),
                                 uh(3), ul(3), scal, D_DIM, 3.f, -0.5f,
                                 FROW | FCOL, 0);
    // Y2 = 0.5*Y1*T2 -> row U4, col U5 (M dead)
    k_nn<<<gm, blk, 0, stream>>>(uh(0), ul(0), uh(3), ul(3), uh(4), ul(4),
                                 uh(5), ul(5), scal, D_DIM, 0.f, 0.5f,
                                 FROW | FCOL, 0);
    // Z2 = 0.25*T2*T1 -> row U1, col U0 (Y1 dead)
    k_nn<<<gm, blk, 0, stream>>>(uh(2), ul(2), uh(7), ul(7), uh(1), ul(1),
                                 uh(0), ul(0), scal, D_DIM, 0.f, 0.25f,
                                 FROW | FCOL, 0);
    int yr = 4, yt = 5, zr = 1, zt = 0;
    int f0 = 2, f1 = 3, f2 = 6, f3 = 7;
    for (int it = 3; it <= 14; ++it) {
      // T = 3I - Z*Y -> f0(row), f1(col)
      k_nn<<<gm, blk, 0, stream>>>(uh(zr), ul(zr), uh(yt), ul(yt), uh(f0),
                                   ul(f0), uh(f1), ul(f1), scal, D_DIM, 3.f,
                                   -1.f, FROW | FCOL, 0);
      // Yn = 0.5 Y*T -> f2, f3
      k_nn<<<gm, blk, 0, stream>>>(uh(yr), ul(yr), uh(f1), ul(f1), uh(f2),
                                   ul(f2), uh(f3), ul(f3), scal, D_DIM, 0.f,
                                   0.5f, FROW | FCOL, 0);
      // Zn = 0.5 T*Z -> old Y units
      k_nn<<<gm, blk, 0, stream>>>(uh(f0), ul(f0), uh(zt), ul(zt), uh(yr),
                                   ul(yr), uh(yt), ul(yt), scal, D_DIM, 0.f,
                                   0.5f, FROW | FCOL, 0);
      int ozr = zr, ozt = zt, of0 = f0, of1 = f1;
      zr = yr; zt = yt;
      yr = f2; yt = f3;
      f0 = ozr; f1 = ozt; f2 = of0; f3 = of1;
    }
    // T15 = 3I - Z14*Y14, col-only -> f0 ; trY15 = 0.5*dot(Y14row, T15col)
    k_nn<<<gm, blk, 0, stream>>>(uh(zr), ul(zr), uh(yt), ul(yt), uh(f1), ul(f1),
                                 uh(f0), ul(f0), scal, D_DIM, 3.f, -1.f, FCOL,
                                 0);
    k_trdot<<<4096, blk, 0, stream>>>(uh(yr), ul(yr), uh(f0), ul(f0),
                                      (double*)(scal + 4));
    k_final2<<<1, 1, 0, stream>>>(scal, (const double*)(scal + 4), out);
    return;
  }

  // ================= FALLBACK (round-4, 64MB) =================
  u16* b[8];
  {
    char* pool = (char*)d_ws + 65536;
    for (int i = 0; i < 8; ++i) b[i] = (u16*)(pool + (size_t)i * 8388608);
  }
#define PH(p) b[2 * (p)]
#define PL(p) b[2 * (p) + 1]
  u16* zh = b[4];
  u16* zl = b[6];
  dim3 gm(32, 16);
  k_zsplit<<<8192, blk, 0, stream>>>(za, stat, stat + D_DIM, zh, zl);
  k_gram_mm<<<gm, blk, 0, stream>>>(zh, zl, PH(0), PL(0));
  k_zsplit<<<8192, blk, 0, stream>>>(zb, stat + 2 * D_DIM, stat + 3 * D_DIM,
                                     zh, zl);
  k_gram_mm<<<gm, blk, 0, stream>>>(zh, zl, PH(1), PL(1));
  k_trace_hl<<<1, blk, 0, stream>>>(PH(0), PL(0), scal + 1);
  k_trace_hl<<<1, blk, 0, stream>>>(PH(1), PL(1), scal + 2);
  k_mm<0><<<gm, blk, 0, stream>>>(PH(0), PL(0), PH(1), PL(1), PH(2), PL(2),
                                  scal);
  k_frob_hl<<<4096, blk, 0, stream>>>(PH(2), PL(2), scal);
  k_t1z1<<<4096, blk, 0, stream>>>(PH(2), PL(2), scal, PH(0), PL(0), PH(1),
                                   PL(1));
  k_mm<3><<<gm, blk, 0, stream>>>(PH(2), PL(2), PH(0), PL(0), PH(3), PL(3),
                                  scal);
  int Y = 3, Z = 1, fA = 0, fB = 2;
  for (int it = 2; it <= NS_ITERS; ++it) {
    k_mm<1><<<gm, blk, 0, stream>>>(PH(Z), PL(Z), PH(Y), PL(Y), PH(fA), PL(fA),
                                    scal);
    k_mm<2><<<gm, blk, 0, stream>>>(PH(Y), PL(Y), PH(fA), PL(fA), PH(fB),
                                    PL(fB), scal);
    if (it < NS_ITERS)
      k_mm<2><<<gm, blk, 0, stream>>>(PH(fA), PL(fA), PH(Z), PL(Z), PH(Y),
                                      PL(Y), scal);
    int oy = Y, oz = Z, oa = fA, ob = fB;
    Y = ob; Z = oy; fA = oz; fB = oa;
  }
  k_final<<<1, blk, 0, stream>>>(PH(Y), PL(Y), scal, out);
#undef PH
#undef PL
}

// Round 8
// 3845.293 us; speedup vs baseline: 1.1569x; 1.1569x over previous
//
#include <hip/hip_runtime.h>
#include <math.h>

typedef unsigned short u16;
typedef unsigned int u32;

#define D_DIM 2048
#define N_ROWS 4096
#define EPS_DIAG 1e-3f
#define NS_ITERS 16  // fallback path only

typedef __attribute__((ext_vector_type(8))) short bf16x8;
typedef __attribute__((ext_vector_type(4))) float f32x4;

__device__ __forceinline__ u16 f2bf(float f) {
  u32 u = __float_as_uint(f);
  u += 0x7fffu + ((u >> 16) & 1u);
  return (u16)(u >> 16);
}
__device__ __forceinline__ float bf2f(u16 h) {
  return __uint_as_float(((u32)h) << 16);
}

#define GLD16(g, l)                                        \
  __builtin_amdgcn_global_load_lds(                        \
      (const __attribute__((address_space(1))) void*)(g),  \
      (__attribute__((address_space(3))) void*)(l), 16, 0, 0)

// scal layout (floats): [1]=trA [2]=trB [5]=c  [6..11]=powerA  [16..21]=powerB
// [24..25] = trdot double accumulator (8-byte aligned, no collisions)

// ---------------- column statistics (mean / rstd, ddof=1) ----------------

__global__ __launch_bounds__(256)
void k_colstats(const float* __restrict__ z, float* __restrict__ sum_,
                float* __restrict__ ssq_) {
  const int c = blockIdx.x * 256 + threadIdx.x;
  const int r0 = blockIdx.y * (N_ROWS / 16);
  float s = 0.f, q = 0.f;
#pragma unroll 8
  for (int r = 0; r < N_ROWS / 16; ++r) {
    float v = z[(size_t)(r0 + r) * D_DIM + c];
    s += v;
    q += v * v;
  }
  atomicAdd(&sum_[c], s);
  atomicAdd(&ssq_[c], q);
}

__global__ __launch_bounds__(256)
void k_finalize_stats(float* stat) {
  const int t = blockIdx.x * 256 + threadIdx.x;
  const int g = t >> 11;
  const int c = t & (D_DIM - 1);
  float* base = stat + g * 2 * D_DIM;
  float s = base[c];
  float q = base[D_DIM + c];
  float mean = s * (1.0f / N_ROWS);
  float var = (q - (float)N_ROWS * mean * mean) * (1.0f / (N_ROWS - 1));
  var = fmaxf(var, 1e-30f);
  base[c] = mean;
  base[D_DIM + c] = 1.0f / sqrtf(var);
}

// ================== FAST PATH (needs 128MB + 64KB workspace) ==================

// standardize + split + TRANSPOSE: z[N][D] -> Zt[D][N] bf16 h/l (16MB each)
__global__ __launch_bounds__(256)
void k_zsplit_t(const float* __restrict__ z, const float* __restrict__ mean,
                const float* __restrict__ rstd, u16* __restrict__ Zth,
                u16* __restrict__ Ztl) {
  __shared__ float T[64 * 72];
  const int t = threadIdx.x;
  const int r0 = blockIdx.x * 64;
  const int c0 = blockIdx.y * 64;
#pragma unroll
  for (int p = 0; p < 4; ++p) {
    int row = p * 16 + (t >> 4);
    int c4 = t & 15;
    float4 v = *(const float4*)(z + (size_t)(r0 + row) * D_DIM + c0 + c4 * 4);
    *(float4*)&T[row * 72 + c4 * 4] = v;
  }
  __syncthreads();
  const int c = c0 + (t >> 2);
  const float m = mean[c];
  const float r = rstd[c];
  const int cc = t >> 2;
#pragma unroll
  for (int g = 0; g < 2; ++g) {
    int rbase = g * 32 + (t & 3) * 8;
    u16 hs[8], ls[8];
#pragma unroll
    for (int i = 0; i < 8; ++i) {
      float x = (T[(rbase + i) * 72 + cc] - m) * r;
      hs[i] = f2bf(x);
      ls[i] = f2bf(x - bf2f(hs[i]));
    }
    uint4 ph, pl;
    ph.x = (u32)hs[0] | ((u32)hs[1] << 16);
    ph.y = (u32)hs[2] | ((u32)hs[3] << 16);
    ph.z = (u32)hs[4] | ((u32)hs[5] << 16);
    ph.w = (u32)hs[6] | ((u32)hs[7] << 16);
    pl.x = (u32)ls[0] | ((u32)ls[1] << 16);
    pl.y = (u32)ls[2] | ((u32)ls[3] << 16);
    pl.z = (u32)ls[4] | ((u32)ls[5] << 16);
    pl.w = (u32)ls[6] | ((u32)ls[7] << 16);
    size_t o = (size_t)c * N_ROWS + r0 + rbase;
    *(uint4*)(Zth + o) = ph;
    *(uint4*)(Ztl + o) = pl;
  }
}

#define FINVC 1
#define FTRACE 4
#define FCOL 8
#define FROW 16

// Unified split-bf16 MFMA GEMM body: C = diag*I + pm*(X * W^T).
// X row-major [..][K], W row-major [..][K]. 128x64 tile, dual-layout out.
__device__ __forceinline__ void nn_body(
    u16* lds, const u16* __restrict__ Xh, const u16* __restrict__ Xl,
    const u16* __restrict__ Wh, const u16* __restrict__ Wl,
    u16* __restrict__ Crh, u16* __restrict__ Crl, u16* __restrict__ Cch,
    u16* __restrict__ Ccl, float* __restrict__ scal, int K, float diag,
    float pmul, int flags, int tidx, int bi, int bj) {
  const int tid = threadIdx.x;
  const int lane = tid & 63;
  const int w = tid >> 6;
  const int I = bi * 128;
  const int J = bj * 64;

  size_t xro[2];
  int xbase[2];
#pragma unroll
  for (int p = 0; p < 2; ++p) {
    int s = p * 256 + w * 64 + lane;
    int m = ((s >> 6) << 4) + (s & 15);
    int qq = (s >> 4) & 3;
    xro[p] = (size_t)(I + m) * K + qq * 8;
    xbase[p] = (p * 256 + w * 64) * 8;
  }
  size_t wro;
  {
    int n = w * 16 + (lane & 15);
    wro = (size_t)(J + n) * K + (lane >> 4) * 8;
  }
  const int wb0 = (w * 64) * 8;

  f32x4 acc[2][4];
#pragma unroll
  for (int i = 0; i < 2; ++i)
#pragma unroll
    for (int j = 0; j < 4; ++j) acc[i][j] = (f32x4){0.f, 0.f, 0.f, 0.f};

#define NN_STAGE(k1, buf)                                      \
  {                                                            \
    _Pragma("unroll") for (int p = 0; p < 2; ++p) {            \
      GLD16(Xh + xro[p] + (k1), &lds[(buf) + xbase[p]]);       \
      GLD16(Xl + xro[p] + (k1), &lds[(buf) + 4096 + xbase[p]]);\
    }                                                          \
    GLD16(Wh + wro + (k1), &lds[(buf) + 8192 + wb0]);          \
    GLD16(Wl + wro + (k1), &lds[(buf) + 10240 + wb0]);         \
  }

  NN_STAGE(0, 0);
  __syncthreads();
  const int nk = K >> 5;
  for (int k = 0; k < nk; ++k) {
    const int cur = (k & 1) * 12288;
    const int nxt = 12288 - cur;
    if (k + 1 < nk) NN_STAGE((k + 1) * 32, nxt);
    bf16x8 fxh[2], fxl[2], fwh[4], fwl[4];
#pragma unroll
    for (int i = 0; i < 2; ++i) {
      int sl = ((w * 2 + i) * 64 + lane) * 8;
      fxh[i] = *(const bf16x8*)&lds[cur + sl];
      fxl[i] = *(const bf16x8*)&lds[cur + 4096 + sl];
    }
#pragma unroll
    for (int j = 0; j < 4; ++j) {
      int sl = (j * 64 + lane) * 8;
      fwh[j] = *(const bf16x8*)&lds[cur + 8192 + sl];
      fwl[j] = *(const bf16x8*)&lds[cur + 10240 + sl];
    }
#pragma unroll
    for (int i = 0; i < 2; ++i)
#pragma unroll
      for (int j = 0; j < 4; ++j) {
        acc[i][j] = __builtin_amdgcn_mfma_f32_16x16x32_bf16(fxh[i], fwh[j],
                                                            acc[i][j], 0, 0, 0);
        acc[i][j] = __builtin_amdgcn_mfma_f32_16x16x32_bf16(fxh[i], fwl[j],
                                                            acc[i][j], 0, 0, 0);
        acc[i][j] = __builtin_amdgcn_mfma_f32_16x16x32_bf16(fxl[i], fwh[j],
                                                            acc[i][j], 0, 0, 0);
      }
    __syncthreads();
  }
#undef NN_STAGE

  const int qd = lane >> 4;
  const int nl = lane & 15;
  float pm = pmul;
  if (flags & FINVC) pm = pmul / scal[5];

#define NN_VAL(i, j, r, out)                           \
  {                                                    \
    int gi_ = I + w * 32 + (i)*16 + qd * 4 + (r);      \
    int gj_ = J + (j)*16 + nl;                         \
    out = pm * acc[i][j][r];                           \
    if (gi_ == gj_) out += diag;                       \
  }

  if (flags & FTRACE) {
    float ts = 0.f;
#pragma unroll
    for (int i = 0; i < 2; ++i)
#pragma unroll
      for (int j = 0; j < 4; ++j)
#pragma unroll
        for (int r = 0; r < 4; ++r) {
          int gi = I + w * 32 + i * 16 + qd * 4 + r;
          int gj = J + j * 16 + nl;
          if (gi == gj) {
            float v;
            NN_VAL(i, j, r, v);
            ts += v;
          }
        }
#pragma unroll
    for (int o = 32; o > 0; o >>= 1) ts += __shfl_down(ts, o, 64);
    float* red = (float*)lds;
    if (lane == 0) red[w] = ts;
    __syncthreads();
    if (tid == 0) atomicAdd(&scal[tidx], red[0] + red[1] + red[2] + red[3]);
    __syncthreads();
  }

  // dual-layout store via per-wave LDS transpose (wave region: 32x72 u16)
  const int wbp = w * 2304;
  for (int half = 0; half < 2; ++half) {
#pragma unroll
    for (int i = 0; i < 2; ++i)
#pragma unroll
      for (int j = 0; j < 4; ++j)
#pragma unroll
        for (int r = 0; r < 4; ++r) {
          float v;
          NN_VAL(i, j, r, v);
          u16 hv = f2bf(v);
          u16 sv = half ? f2bf(v - bf2f(hv)) : hv;
          lds[wbp + (i * 16 + qd * 4 + r) * 72 + j * 16 + nl] = sv;
        }
    __syncthreads();
    if (flags & FROW) {
      u16* dst = half ? Crl : Crh;
#pragma unroll
      for (int p2 = 0; p2 < 4; ++p2) {
        int rr = lane >> 1;
        int ch = (lane & 1) + p2 * 2;
        bf16x8 vv = *(const bf16x8*)&lds[wbp + rr * 72 + ch * 8];
        *(bf16x8*)(dst + (size_t)(I + w * 32 + rr) * D_DIM + J + ch * 8) = vv;
      }
    }
    if (flags & FCOL) {
      u16* dst = half ? Ccl : Cch;
#pragma unroll
      for (int jj = 0; jj < 4; ++jj) {
        int c = jj * 16 + (lane >> 2);
        int run = (lane & 3) * 8;
        u16 tp[8];
#pragma unroll
        for (int r2 = 0; r2 < 8; ++r2) tp[r2] = lds[wbp + (run + r2) * 72 + c];
        uint4 pk;
        pk.x = (u32)tp[0] | ((u32)tp[1] << 16);
        pk.y = (u32)tp[2] | ((u32)tp[3] << 16);
        pk.z = (u32)tp[4] | ((u32)tp[5] << 16);
        pk.w = (u32)tp[6] | ((u32)tp[7] << 16);
        *(uint4*)(dst + (size_t)(J + c) * D_DIM + I + w * 32 + run) = pk;
      }
    }
    __syncthreads();
  }
#undef NN_VAL
}

// plain GEMM: grid (bx=J-tiles, by=I-tiles)
__global__ __launch_bounds__(256)
void k_nn(const u16* Xh, const u16* Xl, const u16* Wh, const u16* Wl, u16* Crh,
          u16* Crl, u16* Cch, u16* Ccl, float* scal, int K, float diag,
          float pmul, int flags, int tidx) {
  __shared__ u16 lds[24576];
  nn_body(lds, Xh, Xl, Wh, Wl, Crh, Crl, Cch, Ccl, scal, K, diag, pmul, flags,
          tidx, blockIdx.y, blockIdx.x);
}

// triangle-grid gram: 1D grid of 272 blocks, bj <= 2bi+1; dual store mirrors
__global__ __launch_bounds__(256)
void k_nn_tri(const u16* Xh, const u16* Xl, u16* Ch, u16* Cl, float* scal,
              int K, float diag, int tidx) {
  __shared__ u16 lds[24576];
  int f = blockIdx.x;
  int bi = (int)(sqrtf((float)f + 0.25f) - 0.5f);
  while (bi * (bi + 1) > f) --bi;
  while ((bi + 1) * (bi + 2) <= f) ++bi;
  int bj = f - bi * (bi + 1);
  nn_body(lds, Xh, Xl, Xh, Xl, Ch, Cl, Ch, Cl, scal, K, diag, 1.0f,
          FROW | FCOL | FTRACE, tidx, bi, bj);
}

// fused pair: grid (32,16,2); z=0: Yn = pm0*X0*W0^T, z=1: Zn = pm1*X1*W1^T
struct NN2Args {
  const u16 *xh0, *xl0, *wh0, *wl0;
  u16 *crh0, *crl0, *cch0, *ccl0;
  const u16 *xh1, *xl1, *wh1, *wl1;
  u16 *crh1, *crl1, *cch1, *ccl1;
  float pm0, pm1;
};

__global__ __launch_bounds__(256)
void k_nn2(NN2Args a, float* scal) {
  __shared__ u16 lds[24576];
  if (blockIdx.z == 0)
    nn_body(lds, a.xh0, a.xl0, a.wh0, a.wl0, a.crh0, a.crl0, a.cch0, a.ccl0,
            scal, D_DIM, 0.f, a.pm0, FROW | FCOL, 0, blockIdx.y, blockIdx.x);
  else
    nn_body(lds, a.xh1, a.xl1, a.wh1, a.wl1, a.crh1, a.crl1, a.cch1, a.ccl1,
            scal, D_DIM, 0.f, a.pm1, FROW | FCOL, 0, blockIdx.y, blockIdx.x);
}

// ---------------- power iteration for lambda_max ----------------

__global__ __launch_bounds__(256)
void k_pones(float* __restrict__ v, float* __restrict__ snorm) {
  int t = blockIdx.x * 256 + threadIdx.x;
  v[t] = 1.0f;
  if (t == 0) snorm[0] = 1.0f;
}

__global__ __launch_bounds__(256)
void k_gemv(const u16* __restrict__ Ah, const float* __restrict__ vin,
            float* __restrict__ vout, const float* __restrict__ snorm,
            unsigned int* __restrict__ smax) {
  __shared__ float vs[D_DIM];
  float inv = 1.0f / snorm[0];
  for (int i = threadIdx.x; i < D_DIM; i += 256) vs[i] = vin[i] * inv;
  __syncthreads();
  int row = blockIdx.x * 4 + (threadIdx.x >> 6);
  int lane = threadIdx.x & 63;
  const u16* r = Ah + (size_t)row * D_DIM;
  float s = 0.f;
  for (int c0 = lane * 8; c0 < D_DIM; c0 += 512) {
    uint4 p = *(const uint4*)(r + c0);
    u32 w4[4] = {p.x, p.y, p.z, p.w};
#pragma unroll
    for (int q = 0; q < 4; ++q) {
      s += bf2f((u16)(w4[q] & 0xffff)) * vs[c0 + 2 * q];
      s += bf2f((u16)(w4[q] >> 16)) * vs[c0 + 2 * q + 1];
    }
  }
#pragma unroll
  for (int o = 32; o > 0; o >>= 1) s += __shfl_down(s, o, 64);
  if (lane == 0) {
    vout[row] = s;
    atomicMax(smax, __float_as_uint(fabsf(s)));
  }
}

__global__ void k_setc(float* scal) {
  scal[5] = 1.1f * scal[11] * scal[21];
}

// T1 = 3I - M/c in BOTH layouts (c = scal[5])
__global__ __launch_bounds__(256)
void k_t1(const u16* __restrict__ Mrh, const u16* __restrict__ Mrl,
          const u16* __restrict__ Mth, const u16* __restrict__ Mtl,
          const float* __restrict__ scal, u16* __restrict__ Trh,
          u16* __restrict__ Trl, u16* __restrict__ Tth, u16* __restrict__ Ttl) {
  size_t t = (size_t)blockIdx.x * 256 + threadIdx.x;
  float invc = 1.0f / scal[5];
  size_t e = t * 4;
  int i = (int)(e >> 11);
  int j0 = (int)(e & (D_DIM - 1));
#pragma unroll
  for (int pass = 0; pass < 2; ++pass) {
    const u16* sh = pass ? Mth : Mrh;
    const u16* sl = pass ? Mtl : Mrl;
    u16* dh = pass ? Tth : Trh;
    u16* dl = pass ? Ttl : Trl;
    uint2 hv = ((const uint2*)sh)[t];
    uint2 lv = ((const uint2*)sl)[t];
    u16 hs[4] = {(u16)(hv.x & 0xffff), (u16)(hv.x >> 16), (u16)(hv.y & 0xffff),
                 (u16)(hv.y >> 16)};
    u16 ls[4] = {(u16)(lv.x & 0xffff), (u16)(lv.x >> 16), (u16)(lv.y & 0xffff),
                 (u16)(lv.y >> 16)};
    u16 th[4], tl[4];
#pragma unroll
    for (int c = 0; c < 4; ++c) {
      float m = bf2f(hs[c]) + bf2f(ls[c]);
      float tv = ((i == j0 + c) ? 3.0f : 0.0f) - m * invc;
      th[c] = f2bf(tv);
      tl[c] = f2bf(tv - bf2f(th[c]));
    }
    ((uint2*)dh)[t] = make_uint2((u32)th[0] | ((u32)th[1] << 16),
                                 (u32)th[2] | ((u32)th[3] << 16));
    ((uint2*)dl)[t] = make_uint2((u32)tl[0] | ((u32)tl[1] << 16),
                                 (u32)tl[2] | ((u32)tl[3] << 16));
  }
}

__global__ __launch_bounds__(256)
void k_trdot(const u16* __restrict__ Ah, const u16* __restrict__ Al,
             const u16* __restrict__ Bh, const u16* __restrict__ Bl,
             double* __restrict__ acc) {
  size_t t = (size_t)blockIdx.x * 256 + threadIdx.x;
  uint2 ah = ((const uint2*)Ah)[t], al = ((const uint2*)Al)[t];
  uint2 bh = ((const uint2*)Bh)[t], bl = ((const uint2*)Bl)[t];
  float s = 0.f;
  u32 ha[4] = {ah.x & 0xffffu, ah.x >> 16, ah.y & 0xffffu, ah.y >> 16};
  u32 la[4] = {al.x & 0xffffu, al.x >> 16, al.y & 0xffffu, al.y >> 16};
  u32 hb[4] = {bh.x & 0xffffu, bh.x >> 16, bh.y & 0xffffu, bh.y >> 16};
  u32 lb[4] = {bl.x & 0xffffu, bl.x >> 16, bl.y & 0xffffu, bl.y >> 16};
#pragma unroll
  for (int c = 0; c < 4; ++c)
    s += (bf2f((u16)ha[c]) + bf2f((u16)la[c])) *
         (bf2f((u16)hb[c]) + bf2f((u16)lb[c]));
#pragma unroll
  for (int o = 32; o > 0; o >>= 1) s += __shfl_down(s, o, 64);
  __shared__ float red[4];
  if ((threadIdx.x & 63) == 0) red[threadIdx.x >> 6] = s;
  __syncthreads();
  if (threadIdx.x == 0)
    atomicAdd(acc, (double)(red[0] + red[1] + red[2] + red[3]));
}

// out = trA + trB - sqrt(c)*dot   (trC = sqrt(c)*trY, trY = dot/2)
__global__ void k_final2(const float* __restrict__ scal,
                         const double* __restrict__ dot,
                         float* __restrict__ out) {
  out[0] = scal[1] + scal[2] - sqrtf(scal[5]) * (float)dot[0];
}

// ================== FALLBACK PATH (round-4, 64MB-proven) ==================

__global__ __launch_bounds__(256)
void k_zsplit(const float* __restrict__ z, const float* __restrict__ mean,
              const float* __restrict__ rstd, u16* __restrict__ zh,
              u16* __restrict__ zl) {
  size_t t = (size_t)blockIdx.x * 256 + threadIdx.x;
  int ci = (int)(t & 511);
  float4 v = ((const float4*)z)[t];
  float4 m = ((const float4*)mean)[ci];
  float4 r = ((const float4*)rstd)[ci];
  float x[4] = {(v.x - m.x) * r.x, (v.y - m.y) * r.y, (v.z - m.z) * r.z,
                (v.w - m.w) * r.w};
  u16 h[4], l[4];
#pragma unroll
  for (int i = 0; i < 4; ++i) {
    h[i] = f2bf(x[i]);
    l[i] = f2bf(x[i] - bf2f(h[i]));
  }
  ((uint2*)zh)[t] = make_uint2((u32)h[0] | ((u32)h[1] << 16),
                               (u32)h[2] | ((u32)h[3] << 16));
  ((uint2*)zl)[t] = make_uint2((u32)l[0] | ((u32)l[1] << 16),
                               (u32)l[2] | ((u32)l[3] << 16));
}

__global__ __launch_bounds__(256)
void k_gram_mm(const u16* __restrict__ zh, const u16* __restrict__ zl,
               u16* __restrict__ Oh, u16* __restrict__ Ol) {
  __shared__ u16 lds[24576];
  const int tid = threadIdx.x;
  const int lane = tid & 63;
  const int w = tid >> 6;
  const int I = blockIdx.y * 128;
  const int J = blockIdx.x * 64;
  const int kp = tid >> 4;
  const int nc = tid & 15;
  const int qq = kp >> 2;
  const int kd = (kp & 3) * 2;
  const size_t aro = (size_t)(2 * kp) * D_DIM + I + nc * 8;
  const size_t bro = (size_t)(2 * kp) * D_DIM + J + nc * 4;
  union U4 { uint4 v; u16 s[8]; };
  union U2 { uint2 v; u16 s[4]; };
  U4 ah0, ah1, al0, al1;
  U2 bh0, bh1, bl0, bl1;
  f32x4 acc[2][4];
#pragma unroll
  for (int i = 0; i < 2; ++i)
#pragma unroll
    for (int j = 0; j < 4; ++j) acc[i][j] = (f32x4){0.f, 0.f, 0.f, 0.f};
#define GRAM_LOAD(k1)                         \
  {                                           \
    size_t ao = aro + (size_t)(k1)*D_DIM;     \
    size_t bo = bro + (size_t)(k1)*D_DIM;     \
    ah0.v = *(const uint4*)(zh + ao);         \
    ah1.v = *(const uint4*)(zh + ao + D_DIM); \
    al0.v = *(const uint4*)(zl + ao);         \
    al1.v = *(const uint4*)(zl + ao + D_DIM); \
    bh0.v = *(const uint2*)(zh + bo);         \
    bh1.v = *(const uint2*)(zh + bo + D_DIM); \
    bl0.v = *(const uint2*)(zl + bo);         \
    bl1.v = *(const uint2*)(zl + bo + D_DIM); \
  }
#define GRAM_PACK(buf)                                                       \
  {                                                                          \
    _Pragma("unroll") for (int j = 0; j < 8; ++j) {                          \
      int mc = nc * 8 + j;                                                   \
      int t2 = mc >> 4, ml = mc & 15;                                        \
      int slot = (t2 * 64 + qq * 16 + ml) ^ t2;                              \
      *(u32*)&lds[(buf) + slot * 8 + kd] =                                   \
          (u32)ah0.s[j] | ((u32)ah1.s[j] << 16);                             \
      *(u32*)&lds[(buf) + 4096 + slot * 8 + kd] =                            \
          (u32)al0.s[j] | ((u32)al1.s[j] << 16);                             \
    }                                                                        \
    _Pragma("unroll") for (int j = 0; j < 4; ++j) {                          \
      int n = nc * 4 + j;                                                    \
      int u = n >> 4, nl = n & 15;                                           \
      int slot = (u * 64 + qq * 16 + nl) ^ u;                                \
      *(u32*)&lds[(buf) + 8192 + slot * 8 + kd] =                            \
          (u32)bh0.s[j] | ((u32)bh1.s[j] << 16);                             \
      *(u32*)&lds[(buf) + 10240 + slot * 8 + kd] =                           \
          (u32)bl0.s[j] | ((u32)bl1.s[j] << 16);                             \
    }                                                                        \
  }
  GRAM_LOAD(0);
  GRAM_PACK(0);
  __syncthreads();
  for (int k = 0; k < N_ROWS / 32; ++k) {
    const int cur = (k & 1) * 12288;
    const int nxt = 12288 - cur;
    if (k < N_ROWS / 32 - 1) GRAM_LOAD((k + 1) * 32);
    bf16x8 fah[2], fal[2], fbh[4], fbl[4];
#pragma unroll
    for (int i = 0; i < 2; ++i) {
      int t2 = w * 2 + i;
      int sl = (t2 * 64 + lane) ^ t2;
      fah[i] = *(const bf16x8*)&lds[cur + sl * 8];
      fal[i] = *(const bf16x8*)&lds[cur + 4096 + sl * 8];
    }
#pragma unroll
    for (int j = 0; j < 4; ++j) {
      int sl = (j * 64 + lane) ^ j;
      fbh[j] = *(const bf16x8*)&lds[cur + 8192 + sl * 8];
      fbl[j] = *(const bf16x8*)&lds[cur + 10240 + sl * 8];
    }
#pragma unroll
    for (int i = 0; i < 2; ++i)
#pragma unroll
      for (int j = 0; j < 4; ++j) {
        acc[i][j] = __builtin_amdgcn_mfma_f32_16x16x32_bf16(fah[i], fbh[j],
                                                            acc[i][j], 0, 0, 0);
        acc[i][j] = __builtin_amdgcn_mfma_f32_16x16x32_bf16(fah[i], fbl[j],
                                                            acc[i][j], 0, 0, 0);
        acc[i][j] = __builtin_amdgcn_mfma_f32_16x16x32_bf16(fal[i], fbh[j],
                                                            acc[i][j], 0, 0, 0);
      }
    if (k < N_ROWS / 32 - 1) GRAM_PACK(nxt);
    __syncthreads();
  }
  const int qd = lane >> 4;
  const int nl = lane & 15;
#pragma unroll
  for (int i = 0; i < 2; ++i)
#pragma unroll
    for (int j = 0; j < 4; ++j)
#pragma unroll
      for (int r = 0; r < 4; ++r) {
        int gi = I + w * 32 + i * 16 + qd * 4 + r;
        int gj = J + j * 16 + nl;
        float v = acc[i][j][r] + ((gi == gj) ? EPS_DIAG : 0.f);
        u16 h = f2bf(v);
        u16 l = f2bf(v - bf2f(h));
        Oh[(size_t)gi * D_DIM + gj] = h;
        Ol[(size_t)gi * D_DIM + gj] = l;
      }
#undef GRAM_LOAD
#undef GRAM_PACK
}

template <int MODE>
__global__ __launch_bounds__(256)
void k_mm(const u16* __restrict__ Ph, const u16* __restrict__ Pl,
          const u16* __restrict__ Qh, const u16* __restrict__ Ql,
          u16* __restrict__ Ch, u16* __restrict__ Cl,
          const float* __restrict__ scal) {
  __shared__ u16 lds[24576];
  const int tid = threadIdx.x;
  const int lane = tid & 63;
  const int w = tid >> 6;
  const int I = blockIdx.y * 128;
  const int J = blockIdx.x * 64;
  const int kp = tid >> 4;
  const int nc = tid & 15;
  const int qq = kp >> 2;
  const int kd = (kp & 3) * 2;
  size_t aro[2];
  int acl[2], abase[2];
#pragma unroll
  for (int p = 0; p < 2; ++p) {
    int s = p * 256 + w * 64 + lane;
    aro[p] = (size_t)(I + (s >> 6) * 16 + (s & 15)) * D_DIM;
    acl[p] = ((s >> 4) & 3) * 8;
    abase[p] = (p * 256 + w * 64) * 8;
  }
  const size_t bro = (size_t)(2 * kp) * D_DIM + J + nc * 4;
  union U2 { uint2 v; u16 s[4]; };
  U2 bh0, bh1, bl0, bl1;
  f32x4 acc[2][4];
#pragma unroll
  for (int i = 0; i < 2; ++i)
#pragma unroll
    for (int j = 0; j < 4; ++j) acc[i][j] = (f32x4){0.f, 0.f, 0.f, 0.f};
#define MM_STAGE_A(k1, buf)                                              \
  {                                                                      \
    _Pragma("unroll") for (int p = 0; p < 2; ++p) {                      \
      GLD16(Ph + aro[p] + (k1) + acl[p], &lds[(buf) + abase[p]]);        \
      GLD16(Pl + aro[p] + (k1) + acl[p], &lds[(buf) + 4096 + abase[p]]); \
    }                                                                    \
  }
#define MM_LOAD_B(k1)                         \
  {                                           \
    size_t bo = bro + (size_t)(k1)*D_DIM;     \
    bh0.v = *(const uint2*)(Qh + bo);         \
    bh1.v = *(const uint2*)(Qh + bo + D_DIM); \
    bl0.v = *(const uint2*)(Ql + bo);         \
    bl1.v = *(const uint2*)(Ql + bo + D_DIM); \
  }
#define MM_PACK_B(buf)                                                       \
  {                                                                          \
    _Pragma("unroll") for (int j = 0; j < 4; ++j) {                          \
      int n = nc * 4 + j;                                                    \
      int u = n >> 4, nl2 = n & 15;                                          \
      int slot = (u * 64 + qq * 16 + nl2) ^ u;                               \
      *(u32*)&lds[(buf) + 8192 + slot * 8 + kd] =                            \
          (u32)bh0.s[j] | ((u32)bh1.s[j] << 16);                             \
      *(u32*)&lds[(buf) + 10240 + slot * 8 + kd] =                           \
          (u32)bl0.s[j] | ((u32)bl1.s[j] << 16);                             \
    }                                                                        \
  }
  MM_STAGE_A(0, 0);
  MM_LOAD_B(0);
  MM_PACK_B(0);
  __syncthreads();
  for (int k = 0; k < D_DIM / 32; ++k) {
    const int cur = (k & 1) * 12288;
    const int nxt = 12288 - cur;
    if (k < D_DIM / 32 - 1) {
      MM_STAGE_A((k + 1) * 32, nxt);
      MM_LOAD_B((k + 1) * 32);
    }
    bf16x8 fah[2], fal[2], fbh[4], fbl[4];
#pragma unroll
    for (int i = 0; i < 2; ++i) {
      int t2 = w * 2 + i;
      fah[i] = *(const bf16x8*)&lds[cur + (t2 * 64 + lane) * 8];
      fal[i] = *(const bf16x8*)&lds[cur + 4096 + (t2 * 64 + lane) * 8];
    }
#pragma unroll
    for (int j = 0; j < 4; ++j) {
      int sl = (j * 64 + lane) ^ j;
      fbh[j] = *(const bf16x8*)&lds[cur + 8192 + sl * 8];
      fbl[j] = *(const bf16x8*)&lds[cur + 10240 + sl * 8];
    }
#pragma unroll
    for (int i = 0; i < 2; ++i)
#pragma unroll
      for (int j = 0; j < 4; ++j) {
        acc[i][j] = __builtin_amdgcn_mfma_f32_16x16x32_bf16(fah[i], fbh[j],
                                                            acc[i][j], 0, 0, 0);
        acc[i][j] = __builtin_amdgcn_mfma_f32_16x16x32_bf16(fah[i], fbl[j],
                                                            acc[i][j], 0, 0, 0);
        acc[i][j] = __builtin_amdgcn_mfma_f32_16x16x32_bf16(fal[i], fbh[j],
                                                            acc[i][j], 0, 0, 0);
      }
    if (k < D_DIM / 32 - 1) MM_PACK_B(nxt);
    __syncthreads();
  }
  float mul = (MODE == 2) ? 0.5f : 1.0f;
  if (MODE == 3) mul = 0.5f / sqrtf(scal[0]);
  const int qd = lane >> 4;
  const int nl = lane & 15;
#pragma unroll
  for (int i = 0; i < 2; ++i)
#pragma unroll
    for (int j = 0; j < 4; ++j)
#pragma unroll
      for (int r = 0; r < 4; ++r) {
        int gi = I + w * 32 + i * 16 + qd * 4 + r;
        int gj = J + j * 16 + nl;
        float v = acc[i][j][r];
        if (MODE == 1)
          v = ((gi == gj) ? 3.0f : 0.0f) - v;
        else
          v *= mul;
        u16 h = f2bf(v);
        u16 l = f2bf(v - bf2f(h));
        Ch[(size_t)gi * D_DIM + gj] = h;
        Cl[(size_t)gi * D_DIM + gj] = l;
      }
#undef MM_STAGE_A
#undef MM_LOAD_B
#undef MM_PACK_B
}

__global__ __launch_bounds__(256)
void k_frob_hl(const u16* __restrict__ mh, const u16* __restrict__ ml,
               float* __restrict__ c2) {
  size_t t = (size_t)blockIdx.x * 256 + threadIdx.x;
  uint2 hv = ((const uint2*)mh)[t];
  uint2 lv = ((const uint2*)ml)[t];
  float v0 = bf2f((u16)(hv.x & 0xffff)) + bf2f((u16)(lv.x & 0xffff));
  float v1 = bf2f((u16)(hv.x >> 16)) + bf2f((u16)(lv.x >> 16));
  float v2 = bf2f((u16)(hv.y & 0xffff)) + bf2f((u16)(lv.y & 0xffff));
  float v3 = bf2f((u16)(hv.y >> 16)) + bf2f((u16)(lv.y >> 16));
  float q = v0 * v0 + v1 * v1 + v2 * v2 + v3 * v3;
#pragma unroll
  for (int o = 32; o > 0; o >>= 1) q += __shfl_down(q, o, 64);
  __shared__ float red[4];
  if ((threadIdx.x & 63) == 0) red[threadIdx.x >> 6] = q;
  __syncthreads();
  if (threadIdx.x == 0) atomicAdd(c2, red[0] + red[1] + red[2] + red[3]);
}

__global__ __launch_bounds__(256)
void k_t1z1(const u16* __restrict__ Mh, const u16* __restrict__ Ml,
            const float* __restrict__ scal, u16* __restrict__ Th,
            u16* __restrict__ Tl, u16* __restrict__ Zh, u16* __restrict__ Zl) {
  size_t t = (size_t)blockIdx.x * 256 + threadIdx.x;
  float invc = 1.0f / sqrtf(scal[0]);
  size_t e = t * 4;
  int i = (int)(e >> 11);
  int j0 = (int)(e & (D_DIM - 1));
  uint2 hv = ((const uint2*)Mh)[t];
  uint2 lv = ((const uint2*)Ml)[t];
  u16 hs[4] = {(u16)(hv.x & 0xffff), (u16)(hv.x >> 16), (u16)(hv.y & 0xffff),
               (u16)(hv.y >> 16)};
  u16 ls[4] = {(u16)(lv.x & 0xffff), (u16)(lv.x >> 16), (u16)(lv.y & 0xffff),
               (u16)(lv.y >> 16)};
  u16 th[4], tl[4], zh[4], zl[4];
#pragma unroll
  for (int c = 0; c < 4; ++c) {
    float m = bf2f(hs[c]) + bf2f(ls[c]);
    float tv = ((i == j0 + c) ? 3.0f : 0.0f) - m * invc;
    th[c] = f2bf(tv);
    tl[c] = f2bf(tv - bf2f(th[c]));
    float zv = 0.5f * tv;
    zh[c] = f2bf(zv);
    zl[c] = f2bf(zv - bf2f(zh[c]));
  }
  ((uint2*)Th)[t] = make_uint2((u32)th[0] | ((u32)th[1] << 16),
                               (u32)th[2] | ((u32)th[3] << 16));
  ((uint2*)Tl)[t] = make_uint2((u32)tl[0] | ((u32)tl[1] << 16),
                               (u32)tl[2] | ((u32)tl[3] << 16));
  ((uint2*)Zh)[t] = make_uint2((u32)zh[0] | ((u32)zh[1] << 16),
                               (u32)zh[2] | ((u32)zh[3] << 16));
  ((uint2*)Zl)[t] = make_uint2((u32)zl[0] | ((u32)zl[1] << 16),
                               (u32)zl[2] | ((u32)zl[3] << 16));
}

__global__ __launch_bounds__(256)
void k_trace_hl(const u16* __restrict__ mh, const u16* __restrict__ ml,
                float* __restrict__ out) {
  __shared__ float red[256];
  float s = 0.f;
  for (int i = threadIdx.x; i < D_DIM; i += 256) {
    size_t d = (size_t)i * (D_DIM + 1);
    s += bf2f(mh[d]) + bf2f(ml[d]);
  }
  red[threadIdx.x] = s;
  __syncthreads();
  for (int o = 128; o > 0; o >>= 1) {
    if (threadIdx.x < o) red[threadIdx.x] += red[threadIdx.x + o];
    __syncthreads();
  }
  if (threadIdx.x == 0) out[0] = red[0];
}

__global__ __launch_bounds__(256)
void k_final(const u16* __restrict__ Yh, const u16* __restrict__ Yl,
             const float* __restrict__ scal, float* __restrict__ out) {
  __shared__ float red[256];
  float s = 0.f;
  for (int i = threadIdx.x; i < D_DIM; i += 256) {
    size_t d = (size_t)i * (D_DIM + 1);
    s += bf2f(Yh[d]) + bf2f(Yl[d]);
  }
  red[threadIdx.x] = s;
  __syncthreads();
  for (int o = 128; o > 0; o >>= 1) {
    if (threadIdx.x < o) red[threadIdx.x] += red[threadIdx.x + o];
    __syncthreads();
  }
  if (threadIdx.x == 0) {
    float sqrtc = sqrtf(sqrtf(scal[0]));
    out[0] = scal[1] + scal[2] - 2.0f * sqrtc * red[0];
  }
}

// ---------------- launch ----------------

extern "C" void kernel_launch(void* const* d_in, const int* in_sizes, int n_in,
                              void* d_out, int out_size, void* d_ws,
                              size_t ws_size, hipStream_t stream) {
  (void)in_sizes; (void)n_in; (void)out_size;
  const float* za = (const float*)d_in[0];
  const float* zb = (const float*)d_in[1];
  float* out = (float*)d_out;
  float* ws = (float*)d_ws;
  float* stat = ws;
  float* scal = ws + 4 * D_DIM;

  hipMemsetAsync(ws, 0, (4 * D_DIM + 32) * sizeof(float), stream);
  dim3 blk(256);
  k_colstats<<<dim3(8, 16), blk, 0, stream>>>(za, stat, stat + D_DIM);
  k_colstats<<<dim3(8, 16), blk, 0, stream>>>(zb, stat + 2 * D_DIM,
                                              stat + 3 * D_DIM);
  k_finalize_stats<<<16, blk, 0, stream>>>(stat);

  const size_t NEED = 65536ull + 8ull * 16 * 1024 * 1024;
  if (ws_size >= NEED) {
    // ================= FAST PATH =================
    char* pool = (char*)d_ws + 65536;
    auto uh = [&](int u) { return (u16*)(pool + (size_t)u * 16777216); };
    auto ul = [&](int u) {
      return (u16*)(pool + (size_t)u * 16777216 + 8388608);
    };
    u16* Zh = (u16*)(pool);             // unit 0 whole (16 MB)
    u16* Zl = (u16*)(pool + 16777216);  // unit 1 whole (16 MB)
    float* va = stat;                   // stats dead after zsplit
    float* vb = stat + D_DIM;
    dim3 gz(64, 32), gm(32, 16);

    // grams (triangle grid, mirrored dual store): A -> U2, B -> U3
    k_zsplit_t<<<gz, blk, 0, stream>>>(za, stat, stat + D_DIM, Zh, Zl);
    k_nn_tri<<<272, blk, 0, stream>>>(Zh, Zl, uh(2), ul(2), scal, N_ROWS,
                                      EPS_DIAG, 1);
    k_zsplit_t<<<gz, blk, 0, stream>>>(zb, stat + 2 * D_DIM, stat + 3 * D_DIM,
                                       Zh, Zl);
    k_nn_tri<<<272, blk, 0, stream>>>(Zh, Zl, uh(3), ul(3), scal, N_ROWS,
                                      EPS_DIAG, 2);

    // power iteration: lambda_max(A) -> scal[11], lambda_max(B) -> scal[21]
    k_pones<<<8, blk, 0, stream>>>(va, scal + 6);
    for (int s = 0; s < 5; ++s) {
      float* vi = (s & 1) ? vb : va;
      float* vo = (s & 1) ? va : vb;
      k_gemv<<<512, blk, 0, stream>>>(uh(2), vi, vo, scal + 6 + s,
                                      (unsigned int*)(scal + 7 + s));
    }
    k_pones<<<8, blk, 0, stream>>>(va, scal + 16);
    for (int s = 0; s < 5; ++s) {
      float* vi = (s & 1) ? vb : va;
      float* vo = (s & 1) ? va : vb;
      k_gemv<<<512, blk, 0, stream>>>(uh(3), vi, vo, scal + 16 + s,
                                      (unsigned int*)(scal + 17 + s));
    }
    k_setc<<<1, 1, 0, stream>>>(scal);

    // M = A*B -> row U4, col U5 (B symmetric => W=B row works)
    k_nn<<<gm, blk, 0, stream>>>(uh(2), ul(2), uh(3), ul(3), uh(4), ul(4),
                                 uh(5), ul(5), scal, D_DIM, 0.f, 1.0f,
                                 FROW | FCOL, 0);
    // T1 = 3I - M/c -> row U6, col U7
    k_t1<<<4096, blk, 0, stream>>>(uh(4), ul(4), uh(5), ul(5), scal, uh(6),
                                   ul(6), uh(7), ul(7));
    // Y1 = (0.5/c) M*T1 -> row U0, col U1
    k_nn<<<gm, blk, 0, stream>>>(uh(4), ul(4), uh(7), ul(7), uh(0), ul(0),
                                 uh(1), ul(1), scal, D_DIM, 0.f, 0.5f,
                                 FROW | FCOL | FINVC, 0);
    // T2 = 3I - 0.5*T1*Y1 -> row U4, col U5  (Z1 = T1/2 implicit)
    k_nn<<<gm, blk, 0, stream>>>(uh(6), ul(6), uh(1), ul(1), uh(4), ul(4),
                                 uh(5), ul(5), scal, D_DIM, 3.f, -0.5f,
                                 FROW | FCOL, 0);
    // fused: Y2 = 0.5*Y1*T2 -> U1,U2 ; Z2 = 0.25*T2*T1 -> U3,U6
    {
      NN2Args a;
      a.xh0 = uh(0); a.xl0 = ul(0); a.wh0 = uh(5); a.wl0 = ul(5);
      a.crh0 = uh(1); a.crl0 = ul(1); a.cch0 = uh(2); a.ccl0 = ul(2);
      a.pm0 = 0.5f;
      a.xh1 = uh(4); a.xl1 = ul(4); a.wh1 = uh(7); a.wl1 = ul(7);
      a.crh1 = uh(3); a.crl1 = ul(3); a.cch1 = uh(6); a.ccl1 = ul(6);
      a.pm1 = 0.25f;
      k_nn2<<<dim3(32, 16, 2), blk, 0, stream>>>(a, scal);
    }
    int Yr = 1, Yt = 2, Zr = 3, Zt = 6;
    int fr0 = 0, fr1 = 4, fr2 = 5, fr3 = 7;
    for (int it = 3; it <= 11; ++it) {
      // T = 3I - Z*Y -> row fr0, col fr1
      k_nn<<<gm, blk, 0, stream>>>(uh(Zr), ul(Zr), uh(Yt), ul(Yt), uh(fr0),
                                   ul(fr0), uh(fr1), ul(fr1), scal, D_DIM, 3.f,
                                   -1.f, FROW | FCOL, 0);
      // fused: Yn = 0.5*Y*T -> fr2,fr3 ; Zn = 0.5*T*Z -> Yt,Zr (dead units)
      NN2Args a;
      a.xh0 = uh(Yr); a.xl0 = ul(Yr); a.wh0 = uh(fr1); a.wl0 = ul(fr1);
      a.crh0 = uh(fr2); a.crl0 = ul(fr2); a.cch0 = uh(fr3); a.ccl0 = ul(fr3);
      a.pm0 = 0.5f;
      a.xh1 = uh(fr0); a.xl1 = ul(fr0); a.wh1 = uh(Zt); a.wl1 = ul(Zt);
      a.crh1 = uh(Yt); a.crl1 = ul(Yt); a.cch1 = uh(Zr); a.ccl1 = ul(Zr);
      a.pm1 = 0.5f;
      k_nn2<<<dim3(32, 16, 2), blk, 0, stream>>>(a, scal);
      int nYr = fr2, nYt = fr3, nZr = Yt, nZt = Zr;
      int nf0 = Yr, nf1 = Zt, nf2 = fr0, nf3 = fr1;
      Yr = nYr; Yt = nYt; Zr = nZr; Zt = nZt;
      fr0 = nf0; fr1 = nf1; fr2 = nf2; fr3 = nf3;
    }
    // step 12: T12 col-only -> fr0 ; trY12 = 0.5*dot(Y11row, T12col)
    k_nn<<<gm, blk, 0, stream>>>(uh(Zr), ul(Zr), uh(Yt), ul(Yt), uh(fr1),
                                 ul(fr1), uh(fr0), ul(fr0), scal, D_DIM, 3.f,
                                 -1.f, FCOL, 0);
    k_trdot<<<4096, blk, 0, stream>>>(uh(Yr), ul(Yr), uh(fr0), ul(fr0),
                                      (double*)(scal + 24));
    k_final2<<<1, 1, 0, stream>>>(scal, (const double*)(scal + 24), out);
    return;
  }

  // ================= FALLBACK (round-4, 64MB) =================
  u16* b[8];
  {
    char* pool = (char*)d_ws + 65536;
    for (int i = 0; i < 8; ++i) b[i] = (u16*)(pool + (size_t)i * 8388608);
  }
#define PH(p) b[2 * (p)]
#define PL(p) b[2 * (p) + 1]
  u16* zh = b[4];
  u16* zl = b[6];
  dim3 gm(32, 16);
  k_zsplit<<<8192, blk, 0, stream>>>(za, stat, stat + D_DIM, zh, zl);
  k_gram_mm<<<gm, blk, 0, stream>>>(zh, zl, PH(0), PL(0));
  k_zsplit<<<8192, blk, 0, stream>>>(zb, stat + 2 * D_DIM, stat + 3 * D_DIM,
                                     zh, zl);
  k_gram_mm<<<gm, blk, 0, stream>>>(zh, zl, PH(1), PL(1));
  k_trace_hl<<<1, blk, 0, stream>>>(PH(0), PL(0), scal + 1);
  k_trace_hl<<<1, blk, 0, stream>>>(PH(1), PL(1), scal + 2);
  k_mm<0><<<gm, blk, 0, stream>>>(PH(0), PL(0), PH(1), PL(1), PH(2), PL(2),
                                  scal);
  k_frob_hl<<<4096, blk, 0, stream>>>(PH(2), PL(2), scal);
  k_t1z1<<<4096, blk, 0, stream>>>(PH(2), PL(2), scal, PH(0), PL(0), PH(1),
                                   PL(1));
  k_mm<3><<<gm, blk, 0, stream>>>(PH(2), PL(2), PH(0), PL(0), PH(3), PL(3),
                                  scal);
  int Y = 3, Z = 1, fA = 0, fB = 2;
  for (int it = 2; it <= NS_ITERS; ++it) {
    k_mm<1><<<gm, blk, 0, stream>>>(PH(Z), PL(Z), PH(Y), PL(Y), PH(fA), PL(fA),
                                    scal);
    k_mm<2><<<gm, blk, 0, stream>>>(PH(Y), PL(Y), PH(fA), PL(fA), PH(fB),
                                    PL(fB), scal);
    if (it < NS_ITERS)
      k_mm<2><<<gm, blk, 0, stream>>>(PH(fA), PL(fA), PH(Z), PL(Z), PH(Y),
                                      PL(Y), scal);
    int oy = Y, oz = Z, oa = fA, ob = fB;
    Y = ob; Z = oy; fA = oz; fB = oa;
  }
  k_final<<<1, blk, 0, stream>>>(PH(Y), PL(Y), scal, out);
#undef PH
#undef PL
}

// Round 9
// 3420.359 us; speedup vs baseline: 1.3007x; 1.1242x over previous
//
#include <hip/hip_runtime.h>
#include <math.h>

typedef unsigned short u16;
typedef unsigned int u32;

#define D_DIM 2048
#define N_ROWS 4096
#define EPS_DIAG 1e-3f
#define NS_ITERS 16  // fallback path only

typedef __attribute__((ext_vector_type(8))) short bf16x8;
typedef __attribute__((ext_vector_type(4))) float f32x4;

__device__ __forceinline__ u16 f2bf(float f) {
  u32 u = __float_as_uint(f);
  u += 0x7fffu + ((u >> 16) & 1u);
  return (u16)(u >> 16);
}
__device__ __forceinline__ float bf2f(u16 h) {
  return __uint_as_float(((u32)h) << 16);
}

#define GLD16(g, l)                                        \
  __builtin_amdgcn_global_load_lds(                        \
      (const __attribute__((address_space(1))) void*)(g),  \
      (__attribute__((address_space(3))) void*)(l), 16, 0, 0)

// scal layout (floats): [1]=trA [2]=trB [5]=c  [6..11]=powerA  [16..21]=powerB
// [24..25] = trdot double accumulator

// XCD-aware bijective tile swizzle for 512-tile grids (16 bi x 32 bj).
// Consecutive-%8 dispatch groups get compact 4x4 super-tile regions.
__device__ __forceinline__ void swz512(int id, int& bi, int& bj) {
  int s = id & 7;
  int j = id >> 3;                 // 0..63
  int st = s + 8 * (j >> 4);       // 0..31 super-tile
  int wi = j & 15;                 // 0..15 within
  bi = (st >> 3) * 4 + (wi >> 2);  // 0..15
  bj = (st & 7) * 4 + (wi & 3);    // 0..31
}

// ---------------- column statistics (both inputs, one launch) ----------------

__global__ __launch_bounds__(256)
void k_colstats2(const float* __restrict__ za, const float* __restrict__ zb,
                 float* __restrict__ stat) {
  const float* z = blockIdx.z ? zb : za;
  float* sum_ = stat + blockIdx.z * 2 * D_DIM;
  float* ssq_ = sum_ + D_DIM;
  const int c = blockIdx.x * 256 + threadIdx.x;
  const int r0 = blockIdx.y * (N_ROWS / 16);
  float s = 0.f, q = 0.f;
#pragma unroll 8
  for (int r = 0; r < N_ROWS / 16; ++r) {
    float v = z[(size_t)(r0 + r) * D_DIM + c];
    s += v;
    q += v * v;
  }
  atomicAdd(&sum_[c], s);
  atomicAdd(&ssq_[c], q);
}

__global__ __launch_bounds__(256)
void k_finalize_stats(float* stat) {
  const int t = blockIdx.x * 256 + threadIdx.x;
  const int g = t >> 11;
  const int c = t & (D_DIM - 1);
  float* base = stat + g * 2 * D_DIM;
  float s = base[c];
  float q = base[D_DIM + c];
  float mean = s * (1.0f / N_ROWS);
  float var = (q - (float)N_ROWS * mean * mean) * (1.0f / (N_ROWS - 1));
  var = fmaxf(var, 1e-30f);
  base[c] = mean;
  base[D_DIM + c] = 1.0f / sqrtf(var);
}

// ================== FAST PATH (needs 128MB + 64KB workspace) ==================

// standardize + split + TRANSPOSE both inputs: z[N][D] -> Zt[D][N] bf16 h/l
__global__ __launch_bounds__(256)
void k_zsplit_t2(const float* __restrict__ za, const float* __restrict__ zb,
                 const float* __restrict__ stat, u16* __restrict__ Zh0,
                 u16* __restrict__ Zl0, u16* __restrict__ Zh1,
                 u16* __restrict__ Zl1) {
  __shared__ float T[64 * 72];
  const float* z = blockIdx.z ? zb : za;
  const float* mean = stat + blockIdx.z * 2 * D_DIM;
  const float* rstd = mean + D_DIM;
  u16* Zth = blockIdx.z ? Zh1 : Zh0;
  u16* Ztl = blockIdx.z ? Zl1 : Zl0;
  const int t = threadIdx.x;
  const int r0 = blockIdx.x * 64;
  const int c0 = blockIdx.y * 64;
#pragma unroll
  for (int p = 0; p < 4; ++p) {
    int row = p * 16 + (t >> 4);
    int c4 = t & 15;
    float4 v = *(const float4*)(z + (size_t)(r0 + row) * D_DIM + c0 + c4 * 4);
    *(float4*)&T[row * 72 + c4 * 4] = v;
  }
  __syncthreads();
  const int c = c0 + (t >> 2);
  const float m = mean[c];
  const float r = rstd[c];
  const int cc = t >> 2;
#pragma unroll
  for (int g = 0; g < 2; ++g) {
    int rbase = g * 32 + (t & 3) * 8;
    u16 hs[8], ls[8];
#pragma unroll
    for (int i = 0; i < 8; ++i) {
      float x = (T[(rbase + i) * 72 + cc] - m) * r;
      hs[i] = f2bf(x);
      ls[i] = f2bf(x - bf2f(hs[i]));
    }
    uint4 ph, pl;
    ph.x = (u32)hs[0] | ((u32)hs[1] << 16);
    ph.y = (u32)hs[2] | ((u32)hs[3] << 16);
    ph.z = (u32)hs[4] | ((u32)hs[5] << 16);
    ph.w = (u32)hs[6] | ((u32)hs[7] << 16);
    pl.x = (u32)ls[0] | ((u32)ls[1] << 16);
    pl.y = (u32)ls[2] | ((u32)ls[3] << 16);
    pl.z = (u32)ls[4] | ((u32)ls[5] << 16);
    pl.w = (u32)ls[6] | ((u32)ls[7] << 16);
    size_t o = (size_t)c * N_ROWS + r0 + rbase;
    *(uint4*)(Zth + o) = ph;
    *(uint4*)(Ztl + o) = pl;
  }
}

#define FINVC 1
#define FTRACE 4
#define FCOL 8
#define FROW 16

// Unified split-bf16 MFMA GEMM body: C = diag*I + pm*(X * W^T).
__device__ __forceinline__ void nn_body(
    u16* lds, const u16* __restrict__ Xh, const u16* __restrict__ Xl,
    const u16* __restrict__ Wh, const u16* __restrict__ Wl,
    u16* __restrict__ Crh, u16* __restrict__ Crl, u16* __restrict__ Cch,
    u16* __restrict__ Ccl, float* __restrict__ scal, int K, float diag,
    float pmul, int flags, int tidx, int bi, int bj) {
  const int tid = threadIdx.x;
  const int lane = tid & 63;
  const int w = tid >> 6;
  const int I = bi * 128;
  const int J = bj * 64;

  size_t xro[2];
  int xbase[2];
#pragma unroll
  for (int p = 0; p < 2; ++p) {
    int s = p * 256 + w * 64 + lane;
    int m = ((s >> 6) << 4) + (s & 15);
    int qq = (s >> 4) & 3;
    xro[p] = (size_t)(I + m) * K + qq * 8;
    xbase[p] = (p * 256 + w * 64) * 8;
  }
  size_t wro;
  {
    int n = w * 16 + (lane & 15);
    wro = (size_t)(J + n) * K + (lane >> 4) * 8;
  }
  const int wb0 = (w * 64) * 8;

  f32x4 acc[2][4];
#pragma unroll
  for (int i = 0; i < 2; ++i)
#pragma unroll
    for (int j = 0; j < 4; ++j) acc[i][j] = (f32x4){0.f, 0.f, 0.f, 0.f};

#define NN_STAGE(k1, buf)                                      \
  {                                                            \
    _Pragma("unroll") for (int p = 0; p < 2; ++p) {            \
      GLD16(Xh + xro[p] + (k1), &lds[(buf) + xbase[p]]);       \
      GLD16(Xl + xro[p] + (k1), &lds[(buf) + 4096 + xbase[p]]);\
    }                                                          \
    GLD16(Wh + wro + (k1), &lds[(buf) + 8192 + wb0]);          \
    GLD16(Wl + wro + (k1), &lds[(buf) + 10240 + wb0]);         \
  }

  NN_STAGE(0, 0);
  __syncthreads();
  const int nk = K >> 5;
  for (int k = 0; k < nk; ++k) {
    const int cur = (k & 1) * 12288;
    const int nxt = 12288 - cur;
    if (k + 1 < nk) NN_STAGE((k + 1) * 32, nxt);
    bf16x8 fxh[2], fxl[2], fwh[4], fwl[4];
#pragma unroll
    for (int i = 0; i < 2; ++i) {
      int sl = ((w * 2 + i) * 64 + lane) * 8;
      fxh[i] = *(const bf16x8*)&lds[cur + sl];
      fxl[i] = *(const bf16x8*)&lds[cur + 4096 + sl];
    }
#pragma unroll
    for (int j = 0; j < 4; ++j) {
      int sl = (j * 64 + lane) * 8;
      fwh[j] = *(const bf16x8*)&lds[cur + 8192 + sl];
      fwl[j] = *(const bf16x8*)&lds[cur + 10240 + sl];
    }
#pragma unroll
    for (int i = 0; i < 2; ++i)
#pragma unroll
      for (int j = 0; j < 4; ++j) {
        acc[i][j] = __builtin_amdgcn_mfma_f32_16x16x32_bf16(fxh[i], fwh[j],
                                                            acc[i][j], 0, 0, 0);
        acc[i][j] = __builtin_amdgcn_mfma_f32_16x16x32_bf16(fxh[i], fwl[j],
                                                            acc[i][j], 0, 0, 0);
        acc[i][j] = __builtin_amdgcn_mfma_f32_16x16x32_bf16(fxl[i], fwh[j],
                                                            acc[i][j], 0, 0, 0);
      }
    __syncthreads();
  }
#undef NN_STAGE

  const int qd = lane >> 4;
  const int nl = lane & 15;
  float pm = pmul;
  if (flags & FINVC) pm = pmul / scal[5];

#define NN_VAL(i, j, r, out)                           \
  {                                                    \
    int gi_ = I + w * 32 + (i)*16 + qd * 4 + (r);      \
    int gj_ = J + (j)*16 + nl;                         \
    out = pm * acc[i][j][r];                           \
    if (gi_ == gj_) out += diag;                       \
  }

  if (flags & FTRACE) {
    float ts = 0.f;
#pragma unroll
    for (int i = 0; i < 2; ++i)
#pragma unroll
      for (int j = 0; j < 4; ++j)
#pragma unroll
        for (int r = 0; r < 4; ++r) {
          int gi = I + w * 32 + i * 16 + qd * 4 + r;
          int gj = J + j * 16 + nl;
          if (gi == gj) {
            float v;
            NN_VAL(i, j, r, v);
            ts += v;
          }
        }
#pragma unroll
    for (int o = 32; o > 0; o >>= 1) ts += __shfl_down(ts, o, 64);
    float* red = (float*)lds;
    if (lane == 0) red[w] = ts;
    __syncthreads();
    if (tid == 0) atomicAdd(&scal[tidx], red[0] + red[1] + red[2] + red[3]);
    __syncthreads();
  }

  // dual-layout store via per-wave LDS transpose (wave region: 32x72 u16)
  const int wbp = w * 2304;
  for (int half = 0; half < 2; ++half) {
#pragma unroll
    for (int i = 0; i < 2; ++i)
#pragma unroll
      for (int j = 0; j < 4; ++j)
#pragma unroll
        for (int r = 0; r < 4; ++r) {
          float v;
          NN_VAL(i, j, r, v);
          u16 hv = f2bf(v);
          u16 sv = half ? f2bf(v - bf2f(hv)) : hv;
          lds[wbp + (i * 16 + qd * 4 + r) * 72 + j * 16 + nl] = sv;
        }
    __syncthreads();
    if (flags & FROW) {
      u16* dst = half ? Crl : Crh;
#pragma unroll
      for (int p2 = 0; p2 < 4; ++p2) {
        int rr = lane >> 1;
        int ch = (lane & 1) + p2 * 2;
        bf16x8 vv = *(const bf16x8*)&lds[wbp + rr * 72 + ch * 8];
        *(bf16x8*)(dst + (size_t)(I + w * 32 + rr) * D_DIM + J + ch * 8) = vv;
      }
    }
    if (flags & FCOL) {
      u16* dst = half ? Ccl : Cch;
#pragma unroll
      for (int jj = 0; jj < 4; ++jj) {
        int c = jj * 16 + (lane >> 2);
        int run = (lane & 3) * 8;
        u16 tp[8];
#pragma unroll
        for (int r2 = 0; r2 < 8; ++r2) tp[r2] = lds[wbp + (run + r2) * 72 + c];
        uint4 pk;
        pk.x = (u32)tp[0] | ((u32)tp[1] << 16);
        pk.y = (u32)tp[2] | ((u32)tp[3] << 16);
        pk.z = (u32)tp[4] | ((u32)tp[5] << 16);
        pk.w = (u32)tp[6] | ((u32)tp[7] << 16);
        *(uint4*)(dst + (size_t)(J + c) * D_DIM + I + w * 32 + run) = pk;
      }
    }
    __syncthreads();
  }
#undef NN_VAL
}

// plain GEMM over 512 tiles, XCD-swizzled
__global__ __launch_bounds__(256)
void k_nn(const u16* Xh, const u16* Xl, const u16* Wh, const u16* Wl, u16* Crh,
          u16* Crl, u16* Cch, u16* Ccl, float* scal, int K, float diag,
          float pmul, int flags, int tidx) {
  __shared__ u16 lds[24576];
  int bi, bj;
  swz512(blockIdx.x + (blockIdx.y << 5), bi, bj);
  nn_body(lds, Xh, Xl, Wh, Wl, Crh, Crl, Cch, Ccl, scal, K, diag, pmul, flags,
          tidx, bi, bj);
}

// both triangle grams in ONE launch: 544 blocks (2 x 272)
__global__ __launch_bounds__(256)
void k_nn_tri2(const u16* Xh0, const u16* Xl0, u16* Ch0, u16* Cl0,
               const u16* Xh1, const u16* Xl1, u16* Ch1, u16* Cl1,
               float* scal) {
  __shared__ u16 lds[24576];
  int x = blockIdx.x;
  int g = (x >= 272) ? 1 : 0;
  int f = x - g * 272;
  int bi = (int)(sqrtf((float)f + 0.25f) - 0.5f);
  while (bi * (bi + 1) > f) --bi;
  while ((bi + 1) * (bi + 2) <= f) ++bi;
  int bj = f - bi * (bi + 1);
  if (g)
    nn_body(lds, Xh1, Xl1, Xh1, Xl1, Ch1, Cl1, Ch1, Cl1, scal, N_ROWS,
            EPS_DIAG, 1.0f, FROW | FCOL | FTRACE, 2, bi, bj);
  else
    nn_body(lds, Xh0, Xl0, Xh0, Xl0, Ch0, Cl0, Ch0, Cl0, scal, N_ROWS,
            EPS_DIAG, 1.0f, FROW | FCOL | FTRACE, 1, bi, bj);
}

// fused pair: grid (32,16,2)
struct NN2Args {
  const u16 *xh0, *xl0, *wh0, *wl0;
  u16 *crh0, *crl0, *cch0, *ccl0;
  const u16 *xh1, *xl1, *wh1, *wl1;
  u16 *crh1, *crl1, *cch1, *ccl1;
  float pm0, pm1;
};

__global__ __launch_bounds__(256)
void k_nn2(NN2Args a, float* scal) {
  __shared__ u16 lds[24576];
  int bi, bj;
  swz512(blockIdx.x + (blockIdx.y << 5), bi, bj);
  if (blockIdx.z == 0)
    nn_body(lds, a.xh0, a.xl0, a.wh0, a.wl0, a.crh0, a.crl0, a.cch0, a.ccl0,
            scal, D_DIM, 0.f, a.pm0, FROW | FCOL, 0, bi, bj);
  else
    nn_body(lds, a.xh1, a.xl1, a.wh1, a.wl1, a.crh1, a.crl1, a.cch1, a.ccl1,
            scal, D_DIM, 0.f, a.pm1, FROW | FCOL, 0, bi, bj);
}

// ---------------- power iteration (both chains fused) ----------------

__global__ __launch_bounds__(256)
void k_pones2(float* __restrict__ va, float* __restrict__ vb,
              float* __restrict__ snA, float* __restrict__ snB) {
  int t = blockIdx.x * 256 + threadIdx.x;  // 0..4095
  if (t < D_DIM)
    va[t] = 1.0f;
  else
    vb[t - D_DIM] = 1.0f;
  if (t == 0) {
    snA[0] = 1.0f;
    snB[0] = 1.0f;
  }
}

__global__ __launch_bounds__(256)
void k_gemv2(const u16* __restrict__ Ah, const u16* __restrict__ Bh,
             const float* viA, float* voA, const float* viB, float* voB,
             const float* snA, const float* snB, u32* smA, u32* smB) {
  const int zc = blockIdx.y;
  const u16* Mh = zc ? Bh : Ah;
  const float* vin = zc ? viB : viA;
  float* vout = zc ? voB : voA;
  const float* snorm = zc ? snB : snA;
  u32* smax = zc ? smB : smA;
  __shared__ float vs[D_DIM];
  float inv = 1.0f / snorm[0];
  for (int i = threadIdx.x; i < D_DIM; i += 256) vs[i] = vin[i] * inv;
  __syncthreads();
  int row = blockIdx.x * 4 + (threadIdx.x >> 6);
  int lane = threadIdx.x & 63;
  const u16* r = Mh + (size_t)row * D_DIM;
  float s = 0.f;
  for (int c0 = lane * 8; c0 < D_DIM; c0 += 512) {
    uint4 p = *(const uint4*)(r + c0);
    u32 w4[4] = {p.x, p.y, p.z, p.w};
#pragma unroll
    for (int q = 0; q < 4; ++q) {
      s += bf2f((u16)(w4[q] & 0xffff)) * vs[c0 + 2 * q];
      s += bf2f((u16)(w4[q] >> 16)) * vs[c0 + 2 * q + 1];
    }
  }
#pragma unroll
  for (int o = 32; o > 0; o >>= 1) s += __shfl_down(s, o, 64);
  if (lane == 0) {
    vout[row] = s;
    atomicMax(smax, __float_as_uint(fabsf(s)));
  }
}

__global__ void k_setc(float* scal) {
  scal[5] = 1.1f * scal[11] * scal[21];
}

// T1 = 3I - M/c in BOTH layouts (c = scal[5])
__global__ __launch_bounds__(256)
void k_t1(const u16* __restrict__ Mrh, const u16* __restrict__ Mrl,
          const u16* __restrict__ Mth, const u16* __restrict__ Mtl,
          const float* __restrict__ scal, u16* __restrict__ Trh,
          u16* __restrict__ Trl, u16* __restrict__ Tth, u16* __restrict__ Ttl) {
  size_t t = (size_t)blockIdx.x * 256 + threadIdx.x;
  float invc = 1.0f / scal[5];
  size_t e = t * 4;
  int i = (int)(e >> 11);
  int j0 = (int)(e & (D_DIM - 1));
#pragma unroll
  for (int pass = 0; pass < 2; ++pass) {
    const u16* sh = pass ? Mth : Mrh;
    const u16* sl = pass ? Mtl : Mrl;
    u16* dh = pass ? Tth : Trh;
    u16* dl = pass ? Ttl : Trl;
    uint2 hv = ((const uint2*)sh)[t];
    uint2 lv = ((const uint2*)sl)[t];
    u16 hs[4] = {(u16)(hv.x & 0xffff), (u16)(hv.x >> 16), (u16)(hv.y & 0xffff),
                 (u16)(hv.y >> 16)};
    u16 ls[4] = {(u16)(lv.x & 0xffff), (u16)(lv.x >> 16), (u16)(lv.y & 0xffff),
                 (u16)(lv.y >> 16)};
    u16 th[4], tl[4];
#pragma unroll
    for (int c = 0; c < 4; ++c) {
      float m = bf2f(hs[c]) + bf2f(ls[c]);
      float tv = ((i == j0 + c) ? 3.0f : 0.0f) - m * invc;
      th[c] = f2bf(tv);
      tl[c] = f2bf(tv - bf2f(th[c]));
    }
    ((uint2*)dh)[t] = make_uint2((u32)th[0] | ((u32)th[1] << 16),
                                 (u32)th[2] | ((u32)th[3] << 16));
    ((uint2*)dl)[t] = make_uint2((u32)tl[0] | ((u32)tl[1] << 16),
                                 (u32)tl[2] | ((u32)tl[3] << 16));
  }
}

__global__ __launch_bounds__(256)
void k_trdot(const u16* __restrict__ Ah, const u16* __restrict__ Al,
             const u16* __restrict__ Bh, const u16* __restrict__ Bl,
             double* __restrict__ acc) {
  size_t t = (size_t)blockIdx.x * 256 + threadIdx.x;
  uint2 ah = ((const uint2*)Ah)[t], al = ((const uint2*)Al)[t];
  uint2 bh = ((const uint2*)Bh)[t], bl = ((const uint2*)Bl)[t];
  float s = 0.f;
  u32 ha[4] = {ah.x & 0xffffu, ah.x >> 16, ah.y & 0xffffu, ah.y >> 16};
  u32 la[4] = {al.x & 0xffffu, al.x >> 16, al.y & 0xffffu, al.y >> 16};
  u32 hb[4] = {bh.x & 0xffffu, bh.x >> 16, bh.y & 0xffffu, bh.y >> 16};
  u32 lb[4] = {bl.x & 0xffffu, bl.x >> 16, bl.y & 0xffffu, bl.y >> 16};
#pragma unroll
  for (int c = 0; c < 4; ++c)
    s += (bf2f((u16)ha[c]) + bf2f((u16)la[c])) *
         (bf2f((u16)hb[c]) + bf2f((u16)lb[c]));
#pragma unroll
  for (int o = 32; o > 0; o >>= 1) s += __shfl_down(s, o, 64);
  __shared__ float red[4];
  if ((threadIdx.x & 63) == 0) red[threadIdx.x >> 6] = s;
  __syncthreads();
  if (threadIdx.x == 0)
    atomicAdd(acc, (double)(red[0] + red[1] + red[2] + red[3]));
}

__global__ void k_final2(const float* __restrict__ scal,
                         const double* __restrict__ dot,
                         float* __restrict__ out) {
  out[0] = scal[1] + scal[2] - sqrtf(scal[5]) * (float)dot[0];
}

// ================== FALLBACK PATH (round-4, 64MB-proven) ==================

__global__ __launch_bounds__(256)
void k_zsplit(const float* __restrict__ z, const float* __restrict__ mean,
              const float* __restrict__ rstd, u16* __restrict__ zh,
              u16* __restrict__ zl) {
  size_t t = (size_t)blockIdx.x * 256 + threadIdx.x;
  int ci = (int)(t & 511);
  float4 v = ((const float4*)z)[t];
  float4 m = ((const float4*)mean)[ci];
  float4 r = ((const float4*)rstd)[ci];
  float x[4] = {(v.x - m.x) * r.x, (v.y - m.y) * r.y, (v.z - m.z) * r.z,
                (v.w - m.w) * r.w};
  u16 h[4], l[4];
#pragma unroll
  for (int i = 0; i < 4; ++i) {
    h[i] = f2bf(x[i]);
    l[i] = f2bf(x[i] - bf2f(h[i]));
  }
  ((uint2*)zh)[t] = make_uint2((u32)h[0] | ((u32)h[1] << 16),
                               (u32)h[2] | ((u32)h[3] << 16));
  ((uint2*)zl)[t] = make_uint2((u32)l[0] | ((u32)l[1] << 16),
                               (u32)l[2] | ((u32)l[3] << 16));
}

__global__ __launch_bounds__(256)
void k_gram_mm(const u16* __restrict__ zh, const u16* __restrict__ zl,
               u16* __restrict__ Oh, u16* __restrict__ Ol) {
  __shared__ u16 lds[24576];
  const int tid = threadIdx.x;
  const int lane = tid & 63;
  const int w = tid >> 6;
  const int I = blockIdx.y * 128;
  const int J = blockIdx.x * 64;
  const int kp = tid >> 4;
  const int nc = tid & 15;
  const int qq = kp >> 2;
  const int kd = (kp & 3) * 2;
  const size_t aro = (size_t)(2 * kp) * D_DIM + I + nc * 8;
  const size_t bro = (size_t)(2 * kp) * D_DIM + J + nc * 4;
  union U4 { uint4 v; u16 s[8]; };
  union U2 { uint2 v; u16 s[4]; };
  U4 ah0, ah1, al0, al1;
  U2 bh0, bh1, bl0, bl1;
  f32x4 acc[2][4];
#pragma unroll
  for (int i = 0; i < 2; ++i)
#pragma unroll
    for (int j = 0; j < 4; ++j) acc[i][j] = (f32x4){0.f, 0.f, 0.f, 0.f};
#define GRAM_LOAD(k1)                         \
  {                                           \
    size_t ao = aro + (size_t)(k1)*D_DIM;     \
    size_t bo = bro + (size_t)(k1)*D_DIM;     \
    ah0.v = *(const uint4*)(zh + ao);         \
    ah1.v = *(const uint4*)(zh + ao + D_DIM); \
    al0.v = *(const uint4*)(zl + ao);         \
    al1.v = *(const uint4*)(zl + ao + D_DIM); \
    bh0.v = *(const uint2*)(zh + bo);         \
    bh1.v = *(const uint2*)(zh + bo + D_DIM); \
    bl0.v = *(const uint2*)(zl + bo);         \
    bl1.v = *(const uint2*)(zl + bo + D_DIM); \
  }
#define GRAM_PACK(buf)                                                       \
  {                                                                          \
    _Pragma("unroll") for (int j = 0; j < 8; ++j) {                          \
      int mc = nc * 8 + j;                                                   \
      int t2 = mc >> 4, ml = mc & 15;                                        \
      int slot = (t2 * 64 + qq * 16 + ml) ^ t2;                              \
      *(u32*)&lds[(buf) + slot * 8 + kd] =                                   \
          (u32)ah0.s[j] | ((u32)ah1.s[j] << 16);                             \
      *(u32*)&lds[(buf) + 4096 + slot * 8 + kd] =                            \
          (u32)al0.s[j] | ((u32)al1.s[j] << 16);                             \
    }                                                                        \
    _Pragma("unroll") for (int j = 0; j < 4; ++j) {                          \
      int n = nc * 4 + j;                                                    \
      int u = n >> 4, nl = n & 15;                                           \
      int slot = (u * 64 + qq * 16 + nl) ^ u;                                \
      *(u32*)&lds[(buf) + 8192 + slot * 8 + kd] =                            \
          (u32)bh0.s[j] | ((u32)bh1.s[j] << 16);                             \
      *(u32*)&lds[(buf) + 10240 + slot * 8 + kd] =                           \
          (u32)bl0.s[j] | ((u32)bl1.s[j] << 16);                             \
    }                                                                        \
  }
  GRAM_LOAD(0);
  GRAM_PACK(0);
  __syncthreads();
  for (int k = 0; k < N_ROWS / 32; ++k) {
    const int cur = (k & 1) * 12288;
    const int nxt = 12288 - cur;
    if (k < N_ROWS / 32 - 1) GRAM_LOAD((k + 1) * 32);
    bf16x8 fah[2], fal[2], fbh[4], fbl[4];
#pragma unroll
    for (int i = 0; i < 2; ++i) {
      int t2 = w * 2 + i;
      int sl = (t2 * 64 + lane) ^ t2;
      fah[i] = *(const bf16x8*)&lds[cur + sl * 8];
      fal[i] = *(const bf16x8*)&lds[cur + 4096 + sl * 8];
    }
#pragma unroll
    for (int j = 0; j < 4; ++j) {
      int sl = (j * 64 + lane) ^ j;
      fbh[j] = *(const bf16x8*)&lds[cur + 8192 + sl * 8];
      fbl[j] = *(const bf16x8*)&lds[cur + 10240 + sl * 8];
    }
#pragma unroll
    for (int i = 0; i < 2; ++i)
#pragma unroll
      for (int j = 0; j < 4; ++j) {
        acc[i][j] = __builtin_amdgcn_mfma_f32_16x16x32_bf16(fah[i], fbh[j],
                                                            acc[i][j], 0, 0, 0);
        acc[i][j] = __builtin_amdgcn_mfma_f32_16x16x32_bf16(fah[i], fbl[j],
                                                            acc[i][j], 0, 0, 0);
        acc[i][j] = __builtin_amdgcn_mfma_f32_16x16x32_bf16(fal[i], fbh[j],
                                                            acc[i][j], 0, 0, 0);
      }
    if (k < N_ROWS / 32 - 1) GRAM_PACK(nxt);
    __syncthreads();
  }
  const int qd = lane >> 4;
  const int nl = lane & 15;
#pragma unroll
  for (int i = 0; i < 2; ++i)
#pragma unroll
    for (int j = 0; j < 4; ++j)
#pragma unroll
      for (int r = 0; r < 4; ++r) {
        int gi = I + w * 32 + i * 16 + qd * 4 + r;
        int gj = J + j * 16 + nl;
        float v = acc[i][j][r] + ((gi == gj) ? EPS_DIAG : 0.f);
        u16 h = f2bf(v);
        u16 l = f2bf(v - bf2f(h));
        Oh[(size_t)gi * D_DIM + gj] = h;
        Ol[(size_t)gi * D_DIM + gj] = l;
      }
#undef GRAM_LOAD
#undef GRAM_PACK
}

template <int MODE>
__global__ __launch_bounds__(256)
void k_mm(const u16* __restrict__ Ph, const u16* __restrict__ Pl,
          const u16* __restrict__ Qh, const u16* __restrict__ Ql,
          u16* __restrict__ Ch, u16* __restrict__ Cl,
          const float* __restrict__ scal) {
  __shared__ u16 lds[24576];
  const int tid = threadIdx.x;
  const int lane = tid & 63;
  const int w = tid >> 6;
  const int I = blockIdx.y * 128;
  const int J = blockIdx.x * 64;
  const int kp = tid >> 4;
  const int nc = tid & 15;
  const int qq = kp >> 2;
  const int kd = (kp & 3) * 2;
  size_t aro[2];
  int acl[2], abase[2];
#pragma unroll
  for (int p = 0; p < 2; ++p) {
    int s = p * 256 + w * 64 + lane;
    aro[p] = (size_t)(I + (s >> 6) * 16 + (s & 15)) * D_DIM;
    acl[p] = ((s >> 4) & 3) * 8;
    abase[p] = (p * 256 + w * 64) * 8;
  }
  const size_t bro = (size_t)(2 * kp) * D_DIM + J + nc * 4;
  union U2 { uint2 v; u16 s[4]; };
  U2 bh0, bh1, bl0, bl1;
  f32x4 acc[2][4];
#pragma unroll
  for (int i = 0; i < 2; ++i)
#pragma unroll
    for (int j = 0; j < 4; ++j) acc[i][j] = (f32x4){0.f, 0.f, 0.f, 0.f};
#define MM_STAGE_A(k1, buf)                                              \
  {                                                                      \
    _Pragma("unroll") for (int p = 0; p < 2; ++p) {                      \
      GLD16(Ph + aro[p] + (k1) + acl[p], &lds[(buf) + abase[p]]);        \
      GLD16(Pl + aro[p] + (k1) + acl[p], &lds[(buf) + 4096 + abase[p]]); \
    }                                                                    \
  }
#define MM_LOAD_B(k1)                         \
  {                                           \
    size_t bo = bro + (size_t)(k1)*D_DIM;     \
    bh0.v = *(const uint2*)(Qh + bo);         \
    bh1.v = *(const uint2*)(Qh + bo + D_DIM); \
    bl0.v = *(const uint2*)(Ql + bo);         \
    bl1.v = *(const uint2*)(Ql + bo + D_DIM); \
  }
#define MM_PACK_B(buf)                                                       \
  {                                                                          \
    _Pragma("unroll") for (int j = 0; j < 4; ++j) {                          \
      int n = nc * 4 + j;                                                    \
      int u = n >> 4, nl2 = n & 15;                                          \
      int slot = (u * 64 + qq * 16 + nl2) ^ u;                               \
      *(u32*)&lds[(buf) + 8192 + slot * 8 + kd] =                            \
          (u32)bh0.s[j] | ((u32)bh1.s[j] << 16);                             \
      *(u32*)&lds[(buf) + 10240 + slot * 8 + kd] =                           \
          (u32)bl0.s[j] | ((u32)bl1.s[j] << 16);                             \
    }                                                                        \
  }
  MM_STAGE_A(0, 0);
  MM_LOAD_B(0);
  MM_PACK_B(0);
  __syncthreads();
  for (int k = 0; k < D_DIM / 32; ++k) {
    const int cur = (k & 1) * 12288;
    const int nxt = 12288 - cur;
    if (k < D_DIM / 32 - 1) {
      MM_STAGE_A((k + 1) * 32, nxt);
      MM_LOAD_B((k + 1) * 32);
    }
    bf16x8 fah[2], fal[2], fbh[4], fbl[4];
#pragma unroll
    for (int i = 0; i < 2; ++i) {
      int t2 = w * 2 + i;
      fah[i] = *(const bf16x8*)&lds[cur + (t2 * 64 + lane) * 8];
      fal[i] = *(const bf16x8*)&lds[cur + 4096 + (t2 * 64 + lane) * 8];
    }
#pragma unroll
    for (int j = 0; j < 4; ++j) {
      int sl = (j * 64 + lane) ^ j;
      fbh[j] = *(const bf16x8*)&lds[cur + 8192 + sl * 8];
      fbl[j] = *(const bf16x8*)&lds[cur + 10240 + sl * 8];
    }
#pragma unroll
    for (int i = 0; i < 2; ++i)
#pragma unroll
      for (int j = 0; j < 4; ++j) {
        acc[i][j] = __builtin_amdgcn_mfma_f32_16x16x32_bf16(fah[i], fbh[j],
                                                            acc[i][j], 0, 0, 0);
        acc[i][j] = __builtin_amdgcn_mfma_f32_16x16x32_bf16(fah[i], fbl[j],
                                                            acc[i][j], 0, 0, 0);
        acc[i][j] = __builtin_amdgcn_mfma_f32_16x16x32_bf16(fal[i], fbh[j],
                                                            acc[i][j], 0, 0, 0);
      }
    if (k < D_DIM / 32 - 1) MM_PACK_B(nxt);
    __syncthreads();
  }
  float mul = (MODE == 2) ? 0.5f : 1.0f;
  if (MODE == 3) mul = 0.5f / sqrtf(scal[0]);
  const int qd = lane >> 4;
  const int nl = lane & 15;
#pragma unroll
  for (int i = 0; i < 2; ++i)
#pragma unroll
    for (int j = 0; j < 4; ++j)
#pragma unroll
      for (int r = 0; r < 4; ++r) {
        int gi = I + w * 32 + i * 16 + qd * 4 + r;
        int gj = J + j * 16 + nl;
        float v = acc[i][j][r];
        if (MODE == 1)
          v = ((gi == gj) ? 3.0f : 0.0f) - v;
        else
          v *= mul;
        u16 h = f2bf(v);
        u16 l = f2bf(v - bf2f(h));
        Ch[(size_t)gi * D_DIM + gj] = h;
        Cl[(size_t)gi * D_DIM + gj] = l;
      }
#undef MM_STAGE_A
#undef MM_LOAD_B
#undef MM_PACK_B
}

__global__ __launch_bounds__(256)
void k_frob_hl(const u16* __restrict__ mh, const u16* __restrict__ ml,
               float* __restrict__ c2) {
  size_t t = (size_t)blockIdx.x * 256 + threadIdx.x;
  uint2 hv = ((const uint2*)mh)[t];
  uint2 lv = ((const uint2*)ml)[t];
  float v0 = bf2f((u16)(hv.x & 0xffff)) + bf2f((u16)(lv.x & 0xffff));
  float v1 = bf2f((u16)(hv.x >> 16)) + bf2f((u16)(lv.x >> 16));
  float v2 = bf2f((u16)(hv.y & 0xffff)) + bf2f((u16)(lv.y & 0xffff));
  float v3 = bf2f((u16)(hv.y >> 16)) + bf2f((u16)(lv.y >> 16));
  float q = v0 * v0 + v1 * v1 + v2 * v2 + v3 * v3;
#pragma unroll
  for (int o = 32; o > 0; o >>= 1) q += __shfl_down(q, o, 64);
  __shared__ float red[4];
  if ((threadIdx.x & 63) == 0) red[threadIdx.x >> 6] = q;
  __syncthreads();
  if (threadIdx.x == 0) atomicAdd(c2, red[0] + red[1] + red[2] + red[3]);
}

__global__ __launch_bounds__(256)
void k_t1z1(const u16* __restrict__ Mh, const u16* __restrict__ Ml,
            const float* __restrict__ scal, u16* __restrict__ Th,
            u16* __restrict__ Tl, u16* __restrict__ Zh, u16* __restrict__ Zl) {
  size_t t = (size_t)blockIdx.x * 256 + threadIdx.x;
  float invc = 1.0f / sqrtf(scal[0]);
  size_t e = t * 4;
  int i = (int)(e >> 11);
  int j0 = (int)(e & (D_DIM - 1));
  uint2 hv = ((const uint2*)Mh)[t];
  uint2 lv = ((const uint2*)Ml)[t];
  u16 hs[4] = {(u16)(hv.x & 0xffff), (u16)(hv.x >> 16), (u16)(hv.y & 0xffff),
               (u16)(hv.y >> 16)};
  u16 ls[4] = {(u16)(lv.x & 0xffff), (u16)(lv.x >> 16), (u16)(lv.y & 0xffff),
               (u16)(lv.y >> 16)};
  u16 th[4], tl[4], zh[4], zl[4];
#pragma unroll
  for (int c = 0; c < 4; ++c) {
    float m = bf2f(hs[c]) + bf2f(ls[c]);
    float tv = ((i == j0 + c) ? 3.0f : 0.0f) - m * invc;
    th[c] = f2bf(tv);
    tl[c] = f2bf(tv - bf2f(th[c]));
    float zv = 0.5f * tv;
    zh[c] = f2bf(zv);
    zl[c] = f2bf(zv - bf2f(zh[c]));
  }
  ((uint2*)Th)[t] = make_uint2((u32)th[0] | ((u32)th[1] << 16),
                               (u32)th[2] | ((u32)th[3] << 16));
  ((uint2*)Tl)[t] = make_uint2((u32)tl[0] | ((u32)tl[1] << 16),
                               (u32)tl[2] | ((u32)tl[3] << 16));
  ((uint2*)Zh)[t] = make_uint2((u32)zh[0] | ((u32)zh[1] << 16),
                               (u32)zh[2] | ((u32)zh[3] << 16));
  ((uint2*)Zl)[t] = make_uint2((u32)zl[0] | ((u32)zl[1] << 16),
                               (u32)zl[2] | ((u32)zl[3] << 16));
}

__global__ __launch_bounds__(256)
void k_trace_hl(const u16* __restrict__ mh, const u16* __restrict__ ml,
                float* __restrict__ out) {
  __shared__ float red[256];
  float s = 0.f;
  for (int i = threadIdx.x; i < D_DIM; i += 256) {
    size_t d = (size_t)i * (D_DIM + 1);
    s += bf2f(mh[d]) + bf2f(ml[d]);
  }
  red[threadIdx.x] = s;
  __syncthreads();
  for (int o = 128; o > 0; o >>= 1) {
    if (threadIdx.x < o) red[threadIdx.x] += red[threadIdx.x + o];
    __syncthreads();
  }
  if (threadIdx.x == 0) out[0] = red[0];
}

__global__ __launch_bounds__(256)
void k_final(const u16* __restrict__ Yh, const u16* __restrict__ Yl,
             const float* __restrict__ scal, float* __restrict__ out) {
  __shared__ float red[256];
  float s = 0.f;
  for (int i = threadIdx.x; i < D_DIM; i += 256) {
    size_t d = (size_t)i * (D_DIM + 1);
    s += bf2f(Yh[d]) + bf2f(Yl[d]);
  }
  red[threadIdx.x] = s;
  __syncthreads();
  for (int o = 128; o > 0; o >>= 1) {
    if (threadIdx.x < o) red[threadIdx.x] += red[threadIdx.x + o];
    __syncthreads();
  }
  if (threadIdx.x == 0) {
    float sqrtc = sqrtf(sqrtf(scal[0]));
    out[0] = scal[1] + scal[2] - 2.0f * sqrtc * red[0];
  }
}

// ---------------- launch ----------------

extern "C" void kernel_launch(void* const* d_in, const int* in_sizes, int n_in,
                              void* d_out, int out_size, void* d_ws,
                              size_t ws_size, hipStream_t stream) {
  (void)in_sizes; (void)n_in; (void)out_size;
  const float* za = (const float*)d_in[0];
  const float* zb = (const float*)d_in[1];
  float* out = (float*)d_out;
  float* ws = (float*)d_ws;
  float* stat = ws;
  float* scal = ws + 4 * D_DIM;

  hipMemsetAsync(ws, 0, (4 * D_DIM + 32) * sizeof(float), stream);
  dim3 blk(256);

  const size_t NEED = 65536ull + 8ull * 16 * 1024 * 1024;
  if (ws_size >= NEED) {
    // ================= FAST PATH =================
    char* pool = (char*)d_ws + 65536;
    auto uh = [&](int u) { return (u16*)(pool + (size_t)u * 16777216); };
    auto ul = [&](int u) {
      return (u16*)(pool + (size_t)u * 16777216 + 8388608);
    };
    // z-split A: whole U0 (h) + whole U1 (l); B: whole U4 + whole U5
    u16* ZhA = (u16*)(pool);
    u16* ZlA = (u16*)(pool + 1ull * 16777216);
    u16* ZhB = (u16*)(pool + 4ull * 16777216);
    u16* ZlB = (u16*)(pool + 5ull * 16777216);
    dim3 gm(32, 16);

    k_colstats2<<<dim3(8, 16, 2), blk, 0, stream>>>(za, zb, stat);
    k_finalize_stats<<<16, blk, 0, stream>>>(stat);
    k_zsplit_t2<<<dim3(64, 32, 2), blk, 0, stream>>>(za, zb, stat, ZhA, ZlA,
                                                     ZhB, ZlB);
    // both grams, one launch: A -> U2 (trace scal[1]), B -> U3 (scal[2])
    k_nn_tri2<<<544, blk, 0, stream>>>(ZhA, ZlA, uh(2), ul(2), ZhB, ZlB,
                                       uh(3), ul(3), scal);

    // paired power iteration: lambda_max(A)->scal[11], lambda_max(B)->scal[21]
    k_pones2<<<16, blk, 0, stream>>>(stat, stat + 2 * D_DIM, scal + 6,
                                     scal + 16);
    for (int s = 0; s < 5; ++s) {
      const float* viA = (s & 1) ? stat + D_DIM : stat;
      float* voA = (s & 1) ? stat : stat + D_DIM;
      const float* viB = (s & 1) ? stat + 3 * D_DIM : stat + 2 * D_DIM;
      float* voB = (s & 1) ? stat + 2 * D_DIM : stat + 3 * D_DIM;
      k_gemv2<<<dim3(512, 2), blk, 0, stream>>>(
          uh(2), uh(3), viA, voA, viB, voB, scal + 6 + s, scal + 16 + s,
          (u32*)(scal + 7 + s), (u32*)(scal + 17 + s));
    }
    k_setc<<<1, 1, 0, stream>>>(scal);

    // M = A*B -> row U4, col U5 (zsplit-B dead; B symmetric => W=B row)
    k_nn<<<gm, blk, 0, stream>>>(uh(2), ul(2), uh(3), ul(3), uh(4), ul(4),
                                 uh(5), ul(5), scal, D_DIM, 0.f, 1.0f,
                                 FROW | FCOL, 0);
    // T1 = 3I - M/c -> row U6, col U7
    k_t1<<<4096, blk, 0, stream>>>(uh(4), ul(4), uh(5), ul(5), scal, uh(6),
                                   ul(6), uh(7), ul(7));
    // Y1 = (0.5/c) M*T1 -> row U0, col U1 (zsplit-A dead)
    k_nn<<<gm, blk, 0, stream>>>(uh(4), ul(4), uh(7), ul(7), uh(0), ul(0),
                                 uh(1), ul(1), scal, D_DIM, 0.f, 0.5f,
                                 FROW | FCOL | FINVC, 0);
    // T2 = 3I - 0.5*T1*Y1 -> row U4, col U5 (M dead; Z1 = T1/2 implicit)
    k_nn<<<gm, blk, 0, stream>>>(uh(6), ul(6), uh(1), ul(1), uh(4), ul(4),
                                 uh(5), ul(5), scal, D_DIM, 3.f, -0.5f,
                                 FROW | FCOL, 0);
    // fused: Y2 = 0.5*Y1*T2 -> U1(row),U2(col) ; Z2 = 0.25*T2*T1 -> U3,U6
    {
      NN2Args a;
      a.xh0 = uh(0); a.xl0 = ul(0); a.wh0 = uh(5); a.wl0 = ul(5);
      a.crh0 = uh(1); a.crl0 = ul(1); a.cch0 = uh(2); a.ccl0 = ul(2);
      a.pm0 = 0.5f;
      a.xh1 = uh(4); a.xl1 = ul(4); a.wh1 = uh(7); a.wl1 = ul(7);
      a.crh1 = uh(3); a.crl1 = ul(3); a.cch1 = uh(6); a.ccl1 = ul(6);
      a.pm1 = 0.25f;
      k_nn2<<<dim3(32, 16, 2), blk, 0, stream>>>(a, scal);
    }
    int Yr = 1, Yt = 2, Zr = 3, Zt = 6;
    int fr0 = 0, fr1 = 4, fr2 = 5, fr3 = 7;
    for (int it = 3; it <= 10; ++it) {
      // T = 3I - Z*Y -> row fr0, col fr1
      k_nn<<<gm, blk, 0, stream>>>(uh(Zr), ul(Zr), uh(Yt), ul(Yt), uh(fr0),
                                   ul(fr0), uh(fr1), ul(fr1), scal, D_DIM, 3.f,
                                   -1.f, FROW | FCOL, 0);
      // fused: Yn = 0.5*Y*T -> fr2,fr3 ; Zn = 0.5*T*Z -> Yt,Zr (dead units)
      NN2Args a;
      a.xh0 = uh(Yr); a.xl0 = ul(Yr); a.wh0 = uh(fr1); a.wl0 = ul(fr1);
      a.crh0 = uh(fr2); a.crl0 = ul(fr2); a.cch0 = uh(fr3); a.ccl0 = ul(fr3);
      a.pm0 = 0.5f;
      a.xh1 = uh(fr0); a.xl1 = ul(fr0); a.wh1 = uh(Zt); a.wl1 = ul(Zt);
      a.crh1 = uh(Yt); a.crl1 = ul(Yt); a.cch1 = uh(Zr); a.ccl1 = ul(Zr);
      a.pm1 = 0.5f;
      k_nn2<<<dim3(32, 16, 2), blk, 0, stream>>>(a, scal);
      int nYr = fr2, nYt = fr3, nZr = Yt, nZt = Zr;
      int nf0 = Yr, nf1 = Zt, nf2 = fr0, nf3 = fr1;
      Yr = nYr; Yt = nYt; Zr = nZr; Zt = nZt;
      fr0 = nf0; fr1 = nf1; fr2 = nf2; fr3 = nf3;
    }
    // step 11: T11 col-only -> fr0 ; trY11 = 0.5*dot(Y10 row, T11 col)
    k_nn<<<gm, blk, 0, stream>>>(uh(Zr), ul(Zr), uh(Yt), ul(Yt), uh(fr1),
                                 ul(fr1), uh(fr0), ul(fr0), scal, D_DIM, 3.f,
                                 -1.f, FCOL, 0);
    k_trdot<<<4096, blk, 0, stream>>>(uh(Yr), ul(Yr), uh(fr0), ul(fr0),
                                      (double*)(scal + 24));
    k_final2<<<1, 1, 0, stream>>>(scal, (const double*)(scal + 24), out);
    return;
  }

  // ================= FALLBACK (round-4, 64MB) =================
  k_colstats2<<<dim3(8, 16, 2), blk, 0, stream>>>(za, zb, stat);
  k_finalize_stats<<<16, blk, 0, stream>>>(stat);
  u16* b[8];
  {
    char* pool = (char*)d_ws + 65536;
    for (int i = 0; i < 8; ++i) b[i] = (u16*)(pool + (size_t)i * 8388608);
  }
#define PH(p) b[2 * (p)]
#define PL(p) b[2 * (p) + 1]
  u16* zh = b[4];
  u16* zl = b[6];
  dim3 gm(32, 16);
  k_zsplit<<<8192, blk, 0, stream>>>(za, stat, stat + D_DIM, zh, zl);
  k_gram_mm<<<gm, blk, 0, stream>>>(zh, zl, PH(0), PL(0));
  k_zsplit<<<8192, blk, 0, stream>>>(zb, stat + 2 * D_DIM, stat + 3 * D_DIM,
                                     zh, zl);
  k_gram_mm<<<gm, blk, 0, stream>>>(zh, zl, PH(1), PL(1));
  k_trace_hl<<<1, blk, 0, stream>>>(PH(0), PL(0), scal + 1);
  k_trace_hl<<<1, blk, 0, stream>>>(PH(1), PL(1), scal + 2);
  k_mm<0><<<gm, blk, 0, stream>>>(PH(0), PL(0), PH(1), PL(1), PH(2), PL(2),
                                  scal);
  k_frob_hl<<<4096, blk, 0, stream>>>(PH(2), PL(2), scal);
  k_t1z1<<<4096, blk, 0, stream>>>(PH(2), PL(2), scal, PH(0), PL(0), PH(1),
                                   PL(1));
  k_mm<3><<<gm, blk, 0, stream>>>(PH(2), PL(2), PH(0), PL(0), PH(3), PL(3),
                                  scal);
  int Y = 3, Z = 1, fA = 0, fB = 2;
  for (int it = 2; it <= NS_ITERS; ++it) {
    k_mm<1><<<gm, blk, 0, stream>>>(PH(Z), PL(Z), PH(Y), PL(Y), PH(fA), PL(fA),
                                    scal);
    k_mm<2><<<gm, blk, 0, stream>>>(PH(Y), PL(Y), PH(fA), PL(fA), PH(fB),
                                    PL(fB), scal);
    if (it < NS_ITERS)
      k_mm<2><<<gm, blk, 0, stream>>>(PH(fA), PL(fA), PH(Z), PL(Z), PH(Y),
                                      PL(Y), scal);
    int oy = Y, oz = Z, oa = fA, ob = fB;
    Y = ob; Z = oy; fA = oz; fB = oa;
  }
  k_final<<<1, blk, 0, stream>>>(PH(Y), PL(Y), scal, out);
#undef PH
#undef PL
}